// Round 3
// baseline (1077.773 us; speedup 1.0000x reference)
//
#include <hip/hip_runtime.h>
#include <cstdint>

// ---------------- workspace layout (float offsets) ----------------
#define WS_U      0                          // 3*8*512 = 12288
#define WS_C0     12288                      // 24 (unused now)
#define WS_ENTBM  12312                      // 1
#define WS_ENTP   12320                      // 8*512 = 4096
#define WS_P      16416                      // 1536*4096 = 6291456
#define WS_OUT2   WS_P                       // alias (P dead after vout GEMM)
#define WS_GPRE   (WS_P + 786432)            // 3 partials * 262144
#define WS_HFUSED (WS_P + 1572864)           // 262144
#define WS_ENHPRE (WS_P + 1835008)           // 2 partials * 262144
#define WS_VOUT   (WS_P + 6291456)           // 786432
#define WS_HCAT   (WS_VOUT + 786432)         // 786432
#define WS_H      (WS_HCAT + 786432)         // 1536
#define WS_Z      (WS_H + 1536)              // 1536

__device__ __forceinline__ float blk_sum4(float v, float* red, int lane, int wave) {
#pragma unroll
  for (int off = 32; off; off >>= 1) v += __shfl_xor(v, off);
  __syncthreads();
  if (lane == 0) red[wave] = v;
  __syncthreads();
  return red[0] + red[1] + red[2] + red[3];
}

// ---------------- prep: grid (4, 8); m<3 -> u vectors, m==3 -> ent partials ----------------
__global__ __launch_bounds__(256) void prep_kernel(
    const float* __restrict__ qrgb, const float* __restrict__ qnir, const float* __restrict__ qtir,
    const float* __restrict__ inw, const float* __restrict__ inb,
    const float* __restrict__ entw, const float* __restrict__ entb,
    float* __restrict__ ws)
{
  const int m = blockIdx.x, h = blockIdx.y;
  const int tid = threadIdx.x, lane = tid & 63, wave = tid >> 6;
  __shared__ float qvl[64];
  __shared__ float red[4];

  if (m == 3) {
    const float* base = entw + (size_t)h * 64 * 512;
    float acc0 = 0.f, acc1 = 0.f;
#pragma unroll 8
    for (int r = 0; r < 64; r++) {
      acc0 += base[(size_t)r * 512 + tid];
      acc1 += base[(size_t)r * 512 + tid + 256];
    }
    ws[WS_ENTP + h * 512 + tid] = acc0;
    ws[WS_ENTP + h * 512 + tid + 256] = acc1;
    return;
  }

  const float* qry = (m == 0) ? qrgb : (m == 1) ? qnir : qtir;
  float4 q0 = *(const float4*)(qry + 4 * lane);
  float4 q1 = *(const float4*)(qry + 256 + 4 * lane);
#pragma unroll 4
  for (int dd = 0; dd < 16; dd++) {
    const int d = wave * 16 + dd;
    const float* wr = inw + (size_t)(h * 64 + d) * 512;
    float4 w0 = *(const float4*)(wr + 4 * lane);
    float4 w1 = *(const float4*)(wr + 256 + 4 * lane);
    float p = w0.x * q0.x + w0.y * q0.y + w0.z * q0.z + w0.w * q0.w
            + w1.x * q1.x + w1.y * q1.y + w1.z * q1.z + w1.w * q1.w;
#pragma unroll
    for (int off = 32; off; off >>= 1) p += __shfl_xor(p, off);
    if (lane == 0) qvl[d] = p + inb[h * 64 + d];
  }
  __syncthreads();
  float acc0 = 0.f, acc1 = 0.f;
  const float* wk = inw + (size_t)(512 + h * 64) * 512;
#pragma unroll 8
  for (int d = 0; d < 64; d++) {
    float qq = qvl[d];
    acc0 = fmaf(qq, wk[(size_t)d * 512 + tid], acc0);
    acc1 = fmaf(qq, wk[(size_t)d * 512 + tid + 256], acc1);
  }
  ws[WS_U + m * 4096 + h * 512 + tid] = 0.125f * acc0;
  ws[WS_U + m * 4096 + h * 512 + tid + 256] = 0.125f * acc1;
  if (m == 0 && h == 0) {
    float v = entb[tid] + entb[tid + 256];
    float s = blk_sum4(v, red, lane, wave);
    if (tid == 0) ws[WS_ENTBM] = s * (1.f / 512.f);
  }
}

// ---------------- attn_pool: single-pass online softmax ----------------
// Round-1 body (VGPR ~100, no spill) + three deltas:
//  (a) launch_bounds(256,4): VGPR<=128 -> 16 waves/CU cap, 4 blocks/CU resident
//  (b) lacc shrunk to [4][2][512] (16KB): LDS no longer the occupancy limiter
//  (c) owner-side exp: the lane owning head hidx applies deferred-max + exp
//      BEFORE the LDS publish (w,m); hot-path readers do no exp at all.
__global__ __launch_bounds__(256, 4) void attn_pool_kernel(
    const float* __restrict__ trgb, const float* __restrict__ tnir, const float* __restrict__ ttir,
    const float* __restrict__ ws, float* __restrict__ Pout)
{
  const int b = blockIdx.x, m = blockIdx.y;
  const int tid = threadIdx.x, lane = tid & 63, wave = tid >> 6;
  const float* tok = ((m == 0) ? trgb : (m == 1) ? tnir : ttir) + (size_t)b * 129 * 512;
  const float* u = ws + WS_U + m * 4096;

  __shared__ float lacc[4][2][512];   // 16 KB combine stage (2 heads / round)
  __shared__ float lstat[4][16];      // per-wave m[8], s[8]
  __shared__ float2 tsh2[4][8];       // per-row (w, m) per head

  float4 u0[8], u1[8];
#pragma unroll
  for (int h = 0; h < 8; h++) {
    u0[h] = *(const float4*)(u + h * 512 + 4 * lane);
    u1[h] = *(const float4*)(u + h * 512 + 256 + 4 * lane);
  }
  const int s0 = lane & 1, s1 = (lane >> 1) & 1, s2 = (lane >> 2) & 1;
  const int hidx = ((lane & 1) << 2) | (lane & 2) | ((lane >> 2) & 1);

  float acc[8][8];                    // [head][col: 4*lane.. / 256+4*lane..]
  float mh[8], sh[8];
#pragma unroll
  for (int h = 0; h < 8; h++) {
    mh[h] = 0.f; sh[h] = 0.f;
#pragma unroll
    for (int j = 0; j < 8; j++) acc[h][j] = 0.f;
  }

  auto process_row = [&](const float4 a, const float4 c) {
    float p[8];
#pragma unroll
    for (int h = 0; h < 8; h++)
      p[h] = a.x * u0[h].x + a.y * u0[h].y + a.z * u0[h].z + a.w * u0[h].w
           + c.x * u1[h].x + c.y * u1[h].y + c.z * u1[h].z + c.w * u1[h].w;
    // pair-merge head-distributing reduce: after xor4 each lane holds one head;
    // xor8/16/32 complete the 64-lane sum leaving EVERY lane with head hidx's total.
    float q0 = (s0 ? p[4] : p[0]) + __shfl_xor(s0 ? p[0] : p[4], 1);
    float q1 = (s0 ? p[5] : p[1]) + __shfl_xor(s0 ? p[1] : p[5], 1);
    float q2 = (s0 ? p[6] : p[2]) + __shfl_xor(s0 ? p[2] : p[6], 1);
    float q3 = (s0 ? p[7] : p[3]) + __shfl_xor(s0 ? p[3] : p[7], 1);
    float r0 = (s1 ? q2 : q0) + __shfl_xor(s1 ? q0 : q2, 2);
    float r1 = (s1 ? q3 : q1) + __shfl_xor(s1 ? q1 : q3, 2);
    float t  = (s2 ? r1 : r0) + __shfl_xor(s2 ? r0 : r1, 4);
    t += __shfl_xor(t, 8);
    t += __shfl_xor(t, 16);
    t += __shfl_xor(t, 32);
    // owner-side deferred-max + exp for head hidx (threshold 8; cold path uniform)
    float msel = s0 ? (s1 ? (s2 ? mh[7] : mh[6]) : (s2 ? mh[5] : mh[4]))
                    : (s1 ? (s2 ? mh[3] : mh[2]) : (s2 ? mh[1] : mh[0]));
    float mA = (t > msel + 8.f) ? t : msel;
    float wo = __expf(t - mA);
    if (lane < 8) tsh2[wave][hidx] = make_float2(wo, mA);
    // hot path: one b64 broadcast per head, no exp
#pragma unroll
    for (int h = 0; h < 8; h++) {
      float2 wm = tsh2[wave][h];
      if (wm.y > mh[h]) {               // cold, uniform across lanes
        float scl = __expf(mh[h] - wm.y);
        sh[h] *= scl;
#pragma unroll
        for (int j = 0; j < 8; j++) acc[h][j] *= scl;
        mh[h] = wm.y;
      }
      float w = wm.x;
      sh[h] += w;
      acc[h][0] = fmaf(w, a.x, acc[h][0]);
      acc[h][1] = fmaf(w, a.y, acc[h][1]);
      acc[h][2] = fmaf(w, a.z, acc[h][2]);
      acc[h][3] = fmaf(w, a.w, acc[h][3]);
      acc[h][4] = fmaf(w, c.x, acc[h][4]);
      acc[h][5] = fmaf(w, c.y, acc[h][5]);
      acc[h][6] = fmaf(w, c.z, acc[h][6]);
      acc[h][7] = fmaf(w, c.w, acc[h][7]);
    }
  };

  // rows l = wave + 4*i; wave 0 gets 33 rows (incl. 128), waves 1-3 get 32
  const int nrows = (wave == 0) ? 33 : 32;
  const float* r0p = tok + (size_t)wave * 512;
  float4 a0 = *(const float4*)(r0p + 4 * lane);
  float4 c0 = *(const float4*)(r0p + 256 + 4 * lane);
  const float* r1p = tok + (size_t)(wave + 4) * 512;
  float4 a1 = *(const float4*)(r1p + 4 * lane);
  float4 c1 = *(const float4*)(r1p + 256 + 4 * lane);
  for (int i = 0; i + 2 < nrows; i++) {
    const float* np = tok + (size_t)(wave + 4 * (i + 2)) * 512;
    float4 na = *(const float4*)(np + 4 * lane);
    float4 nc = *(const float4*)(np + 256 + 4 * lane);
    process_row(a0, c0);
    a0 = a1; c0 = c1;
    a1 = na; c1 = nc;
  }
  process_row(a0, c0);
  process_row(a1, c1);

  // ---- cross-wave combine ----
  if (lane == 0) {
#pragma unroll
    for (int h = 0; h < 8; h++) {
      lstat[wave][h] = mh[h];
      lstat[wave][8 + h] = sh[h];
    }
  }
  __syncthreads();
  float fw[4][8];
#pragma unroll
  for (int h = 0; h < 8; h++) {
    float m0 = lstat[0][h], m1 = lstat[1][h], m2 = lstat[2][h], m3 = lstat[3][h];
    float Mx = fmaxf(fmaxf(m0, m1), fmaxf(m2, m3));
    float f0 = __expf(m0 - Mx), f1 = __expf(m1 - Mx);
    float f2 = __expf(m2 - Mx), f3 = __expf(m3 - Mx);
    float S = lstat[0][8 + h] * f0 + lstat[1][8 + h] * f1
            + lstat[2][8 + h] * f2 + lstat[3][8 + h] * f3;
    float is = 1.f / S;
    fw[0][h] = f0 * is; fw[1][h] = f1 * is; fw[2][h] = f2 * is; fw[3][h] = f3 * is;
  }
  float* po = Pout + (size_t)(m * 512 + b) * 4096 + 2 * tid;
#pragma unroll
  for (int hb = 0; hb < 8; hb += 2) {
    if (hb) __syncthreads();          // previous round's reads done before reuse
#pragma unroll
    for (int hh = 0; hh < 2; hh++) {
      const int h = hb + hh;
      *(float4*)&lacc[wave][hh][4 * lane] =
          make_float4(acc[h][0], acc[h][1], acc[h][2], acc[h][3]);
      *(float4*)&lacc[wave][hh][256 + 4 * lane] =
          make_float4(acc[h][4], acc[h][5], acc[h][6], acc[h][7]);
    }
    __syncthreads();
#pragma unroll
    for (int hh = 0; hh < 2; hh++) {
      const int h = hb + hh;
      float2 x0 = *(const float2*)&lacc[0][hh][2 * tid];
      float2 x1 = *(const float2*)&lacc[1][hh][2 * tid];
      float2 x2 = *(const float2*)&lacc[2][hh][2 * tid];
      float2 x3 = *(const float2*)&lacc[3][hh][2 * tid];
      float ox = x0.x * fw[0][h] + x1.x * fw[1][h] + x2.x * fw[2][h] + x3.x * fw[3][h];
      float oy = x0.y * fw[0][h] + x1.y * fw[1][h] + x2.y * fw[2][h] + x3.y * fw[3][h];
      *(float2*)(po + h * 512) = make_float2(ox, oy);
    }
  }
}

// ---------------- f32 GEMM: C = A @ B^T (+bias), 64x64 tile, 4x4 micro ----------------
__global__ __launch_bounds__(256) void gemm_bt_kernel(
    const float* __restrict__ A, const float* __restrict__ B,
    const float* __restrict__ bias, float* __restrict__ C,
    int K, int lda, int ldb, int ldc,
    long sA, long sB, long sC, int sBias, int addBias)
{
  A += (long)blockIdx.z * sA;
  B += (long)blockIdx.z * sB;
  C += (long)blockIdx.z * sC;
  const float* bp = bias + (long)blockIdx.z * sBias;
  __shared__ float As[32][68];
  __shared__ float Bs[32][68];
  const int tid = threadIdx.x;
  const int tx = tid & 15, ty = tid >> 4;
  const int rowL = tid >> 3;
  const int colv = (tid & 7) << 2;
  const int m0 = blockIdx.x * 64, n0 = blockIdx.y * 64;
  float acc[4][4] = {};
  for (int k0 = 0; k0 < K; k0 += 32) {
#pragma unroll
    for (int it = 0; it < 2; it++) {
      const int r = rowL + it * 32;
      float4 v = *(const float4*)(A + (size_t)(m0 + r) * lda + k0 + colv);
      As[colv + 0][r] = v.x; As[colv + 1][r] = v.y; As[colv + 2][r] = v.z; As[colv + 3][r] = v.w;
      float4 w = *(const float4*)(B + (size_t)(n0 + r) * ldb + k0 + colv);
      Bs[colv + 0][r] = w.x; Bs[colv + 1][r] = w.y; Bs[colv + 2][r] = w.z; Bs[colv + 3][r] = w.w;
    }
    __syncthreads();
#pragma unroll
    for (int k = 0; k < 32; k++) {
      float4 a4 = *(const float4*)&As[k][ty * 4];
      float4 b4 = *(const float4*)&Bs[k][tx * 4];
      acc[0][0] += a4.x * b4.x; acc[0][1] += a4.x * b4.y; acc[0][2] += a4.x * b4.z; acc[0][3] += a4.x * b4.w;
      acc[1][0] += a4.y * b4.x; acc[1][1] += a4.y * b4.y; acc[1][2] += a4.y * b4.z; acc[1][3] += a4.y * b4.w;
      acc[2][0] += a4.z * b4.x; acc[2][1] += a4.z * b4.y; acc[2][2] += a4.z * b4.z; acc[2][3] += a4.z * b4.w;
      acc[3][0] += a4.w * b4.x; acc[3][1] += a4.w * b4.y; acc[3][2] += a4.w * b4.z; acc[3][3] += a4.w * b4.w;
    }
    __syncthreads();
  }
  float4 bv = make_float4(0.f, 0.f, 0.f, 0.f);
  if (addBias) bv = *(const float4*)(bp + n0 + tx * 4);
#pragma unroll
  for (int i = 0; i < 4; i++) {
    float4 o;
    o.x = acc[i][0] + bv.x; o.y = acc[i][1] + bv.y;
    o.z = acc[i][2] + bv.z; o.w = acc[i][3] + bv.w;
    *(float4*)(C + (size_t)(m0 + ty * 4 + i) * ldc + n0 + tx * 4) = o;
  }
}

// ---------------- LN(attn out) + entropy + z ----------------
__global__ __launch_bounds__(256) void ln_ent_kernel(
    const float* __restrict__ out2,
    const float* __restrict__ lng, const float* __restrict__ lnb,
    const float* __restrict__ ws, float* __restrict__ hcat,
    float* __restrict__ Hout, float* __restrict__ zout)
{
  const int r = blockIdx.x;
  const int mod = r >> 9, b = r & 511;
  const int tid = threadIdx.x, lane = tid & 63, wave = tid >> 6;
  __shared__ float red[4];
  const float* x = out2 + (size_t)r * 512;
  float2 v = *(const float2*)(x + 2 * tid);
  float s = blk_sum4(v.x + v.y, red, lane, wave);
  float sq = blk_sum4(v.x * v.x + v.y * v.y, red, lane, wave);
  float mean = s * (1.f / 512.f);
  float var = sq * (1.f / 512.f) - mean * mean;
  float rstd = rsqrtf(var + 1e-5f);
  float2 g = *(const float2*)(lng + 2 * tid);
  float2 bb = *(const float2*)(lnb + 2 * tid);
  float h0 = (v.x - mean) * rstd * g.x + bb.x;
  float h1 = (v.y - mean) * rstd * g.y + bb.y;
  *(float2*)(hcat + (size_t)b * 1536 + mod * 512 + 2 * tid) = make_float2(h0, h1);
  float2 ep = make_float2(0.f, 0.f);
#pragma unroll
  for (int j = 0; j < 8; j++) {
    float2 t = *(const float2*)(ws + WS_ENTP + j * 512 + 2 * tid);
    ep.x += t.x; ep.y += t.y;
  }
  ep.x *= (1.f / 512.f); ep.y *= (1.f / 512.f);
  float fa0 = fabsf(h0) + 1e-8f, fa1 = fabsf(h1) + 1e-8f;
  float S = blk_sum4(fa0 + fa1, red, lane, wave);
  float zz = blk_sum4(h0 * ep.x + h1 * ep.y, red, lane, wave);
  float invS = 1.f / S;
  float p0 = fa0 * invS, p1 = fa1 * invS;
  float t = blk_sum4(p0 * logf(p0 + 1e-8f) + p1 * logf(p1 + 1e-8f), red, lane, wave);
  if (tid == 0) {
    Hout[mod * 512 + b] = -t;
    zout[mod * 512 + b] = zz + ws[WS_ENTBM];
  }
}

// ---------------- gate LN/relu/sigmoid + entropy softmax + fuse ----------------
__global__ __launch_bounds__(256) void gate_fuse_kernel(
    const float* __restrict__ gpre, const float* __restrict__ glng, const float* __restrict__ glnb,
    const float* __restrict__ gw2, const float* __restrict__ gb2, const float* __restrict__ gb1,
    const float* __restrict__ araw, const float* __restrict__ hcat,
    const float* __restrict__ H, const float* __restrict__ z,
    float* __restrict__ hfused)
{
  const int b = blockIdx.x;
  const int tid = threadIdx.x, lane = tid & 63, wave = tid >> 6;
  __shared__ float red[4];
  float2 v;
  {
    float2 p0 = *(const float2*)(gpre + (size_t)b * 512 + 2 * tid);
    float2 p1 = *(const float2*)(gpre + 262144 + (size_t)b * 512 + 2 * tid);
    float2 p2 = *(const float2*)(gpre + 524288 + (size_t)b * 512 + 2 * tid);
    float2 bi = *(const float2*)(gb1 + 2 * tid);
    v.x = p0.x + p1.x + p2.x + bi.x;
    v.y = p0.y + p1.y + p2.y + bi.y;
  }
  float s = blk_sum4(v.x + v.y, red, lane, wave);
  float sq = blk_sum4(v.x * v.x + v.y * v.y, red, lane, wave);
  float mean = s * (1.f / 512.f), var = sq * (1.f / 512.f) - mean * mean;
  float rstd = rsqrtf(var + 1e-5f);
  float2 g = *(const float2*)(glng + 2 * tid);
  float2 bb = *(const float2*)(glnb + 2 * tid);
  float g0 = fmaxf((v.x - mean) * rstd * g.x + bb.x, 0.f);
  float g1 = fmaxf((v.y - mean) * rstd * g.y + bb.y, 0.f);
  float d0 = blk_sum4(g0 * gw2[2 * tid] + g1 * gw2[2 * tid + 1], red, lane, wave);
  float d1 = blk_sum4(g0 * gw2[512 + 2 * tid] + g1 * gw2[512 + 2 * tid + 1], red, lane, wave);
  float d2 = blk_sum4(g0 * gw2[1024 + 2 * tid] + g1 * gw2[1024 + 2 * tid + 1], red, lane, wave);
  float ga0 = 1.f / (1.f + __expf(-(d0 + gb2[0])));
  float ga1 = 1.f / (1.f + __expf(-(d1 + gb2[1])));
  float ga2 = 1.f / (1.f + __expf(-(d2 + gb2[2])));
  float sc0 = z[b] * __expf(-H[b]);
  float sc1 = z[512 + b] * __expf(-H[512 + b]);
  float sc2 = z[1024 + b] * __expf(-H[1024 + b]);
  float mxs = fmaxf(sc0, fmaxf(sc1, sc2));
  float e0 = __expf(sc0 - mxs), e1 = __expf(sc1 - mxs), e2 = __expf(sc2 - mxs);
  float inv = 1.f / (e0 + e1 + e2);
  e0 *= inv; e1 *= inv; e2 *= inv;
  float alpha = 1.f / (1.f + __expf(-araw[0]));
  const float* hb = hcat + (size_t)b * 1536 + 2 * tid;
  float2 hr = *(const float2*)hb;
  float2 hn = *(const float2*)(hb + 512);
  float2 ht = *(const float2*)(hb + 1024);
  float2 o;
  o.x = alpha * (e0 * hr.x + e1 * hn.x + e2 * ht.x)
      + (1.f - alpha) * (ga0 * hr.x + ga1 * hn.x + ga2 * ht.x);
  o.y = alpha * (e0 * hr.y + e1 * hn.y + e2 * ht.y)
      + (1.f - alpha) * (ga0 * hr.y + ga1 * hn.y + ga2 * ht.y);
  *(float2*)(hfused + (size_t)b * 512 + 2 * tid) = o;
}

// ---------------- final LN(enh) + concat-add ----------------
__global__ __launch_bounds__(256) void final_out_kernel(
    const float* __restrict__ epre, const float* __restrict__ enb,
    const float* __restrict__ elng, const float* __restrict__ elnb,
    const float* __restrict__ hcat, float* __restrict__ out)
{
  const int b = blockIdx.x;
  const int tid = threadIdx.x, lane = tid & 63, wave = tid >> 6;
  __shared__ float red[4];
  float2 v;
  {
    float2 p0 = *(const float2*)(epre + (size_t)b * 512 + 2 * tid);
    float2 p1 = *(const float2*)(epre + 262144 + (size_t)b * 512 + 2 * tid);
    float2 bi = *(const float2*)(enb + 2 * tid);
    v.x = p0.x + p1.x + bi.x;
    v.y = p0.y + p1.y + bi.y;
  }
  float s = blk_sum4(v.x + v.y, red, lane, wave);
  float sq = blk_sum4(v.x * v.x + v.y * v.y, red, lane, wave);
  float mean = s * (1.f / 512.f), var = sq * (1.f / 512.f) - mean * mean;
  float rstd = rsqrtf(var + 1e-5f);
  float2 g = *(const float2*)(elng + 2 * tid);
  float2 bb = *(const float2*)(elnb + 2 * tid);
  float e0 = (v.x - mean) * rstd * g.x + bb.x;
  float e1 = (v.y - mean) * rstd * g.y + bb.y;
  const float* hb = hcat + (size_t)b * 1536 + 2 * tid;
  float* ob = out + (size_t)b * 1536 + 2 * tid;
#pragma unroll
  for (int mm = 0; mm < 3; mm++) {
    float2 hv = *(const float2*)(hb + mm * 512);
    *(float2*)(ob + mm * 512) = make_float2(hv.x + e0, hv.y + e1);
  }
}

extern "C" void kernel_launch(void* const* d_in, const int* in_sizes, int n_in,
                              void* d_out, int out_size, void* d_ws, size_t ws_size,
                              hipStream_t stream)
{
  const float* trgb = (const float*)d_in[0];
  const float* tnir = (const float*)d_in[1];
  const float* ttir = (const float*)d_in[2];
  const float* qrgb = (const float*)d_in[3];
  const float* qnir = (const float*)d_in[4];
  const float* qtir = (const float*)d_in[5];
  const float* inw  = (const float*)d_in[6];
  const float* inb  = (const float*)d_in[7];
  const float* outw = (const float*)d_in[8];
  const float* outb = (const float*)d_in[9];
  const float* alng = (const float*)d_in[10];
  const float* alnb = (const float*)d_in[11];
  const float* entw = (const float*)d_in[12];
  const float* entb = (const float*)d_in[13];
  const float* gw1  = (const float*)d_in[14];
  const float* gb1  = (const float*)d_in[15];
  const float* glng = (const float*)d_in[16];
  const float* glnb = (const float*)d_in[17];
  const float* gw2  = (const float*)d_in[18];
  const float* gb2  = (const float*)d_in[19];
  const float* araw = (const float*)d_in[20];
  const float* enw  = (const float*)d_in[21];
  const float* enb  = (const float*)d_in[22];
  const float* elng = (const float*)d_in[23];
  const float* elnb = (const float*)d_in[24];
  float* ws = (float*)d_ws;
  float* out = (float*)d_out;

  hipLaunchKernelGGL(prep_kernel, dim3(4, 8), dim3(256), 0, stream,
                     qrgb, qnir, qtir, inw, inb, entw, entb, ws);
  hipLaunchKernelGGL(attn_pool_kernel, dim3(512, 3), dim3(256), 0, stream,
                     trgb, tnir, ttir, ws, ws + WS_P);
  // vout = P @ Wv^T + bv (batched over 8 heads)
  hipLaunchKernelGGL(gemm_bt_kernel, dim3(24, 1, 8), dim3(256), 0, stream,
                     ws + WS_P, inw + (size_t)1024 * 512, inb + 1024, ws + WS_VOUT,
                     512, 4096, 512, 512,
                     (long)512, (long)64 * 512, (long)64, 64, 1);
  // out2 = vout @ Wo^T + bo
  hipLaunchKernelGGL(gemm_bt_kernel, dim3(24, 8, 1), dim3(256), 0, stream,
                     ws + WS_VOUT, outw, outb, ws + WS_OUT2,
                     512, 512, 512, 512, 0L, 0L, 0L, 0, 1);
  hipLaunchKernelGGL(ln_ent_kernel, dim3(1536), dim3(256), 0, stream,
                     ws + WS_OUT2, alng, alnb, ws, ws + WS_HCAT, ws + WS_H, ws + WS_Z);
  // g_pre partials = hcat @ gate_w1^T (split-K x3, bias added in gate_fuse)
  hipLaunchKernelGGL(gemm_bt_kernel, dim3(8, 8, 3), dim3(256), 0, stream,
                     ws + WS_HCAT, gw1, gb1, ws + WS_GPRE,
                     512, 1536, 1536, 512,
                     (long)512, (long)512, (long)262144, 0, 0);
  hipLaunchKernelGGL(gate_fuse_kernel, dim3(512), dim3(256), 0, stream,
                     ws + WS_GPRE, glng, glnb, gw2, gb2, gb1, araw,
                     ws + WS_HCAT, ws + WS_H, ws + WS_Z, ws + WS_HFUSED);
  // enh partials = h_fused @ enh_w^T (split-K x2, bias added in final_out)
  hipLaunchKernelGGL(gemm_bt_kernel, dim3(8, 8, 2), dim3(256), 0, stream,
                     ws + WS_HFUSED, enw, enb, ws + WS_ENHPRE,
                     256, 512, 512, 512,
                     (long)256, (long)256, (long)262144, 0, 0);
  hipLaunchKernelGGL(final_out_kernel, dim3(512), dim3(256), 0, stream,
                     ws + WS_ENHPRE, enb, elng, elnb, ws + WS_HCAT, out);
}

// Round 4
// 445.927 us; speedup vs baseline: 2.4169x; 2.4169x over previous
//
#include <hip/hip_runtime.h>
#include <cstdint>

// ---------------- workspace layout (float offsets) ----------------
#define WS_U      0                          // 3*8*512 = 12288
#define WS_C0     12288                      // 24 (unused now)
#define WS_ENTBM  12312                      // 1
#define WS_ENTP   12320                      // 8*512 = 4096
#define WS_P      16416                      // 1536*4096 = 6291456
#define WS_OUT2   WS_P                       // alias (P dead after vout GEMM)
#define WS_GPRE   (WS_P + 786432)            // 3 partials * 262144
#define WS_HFUSED (WS_P + 1572864)           // 262144
#define WS_ENHPRE (WS_P + 1835008)           // 2 partials * 262144
#define WS_VOUT   (WS_P + 6291456)           // 786432
#define WS_HCAT   (WS_VOUT + 786432)         // 786432
#define WS_H      (WS_HCAT + 786432)         // 1536
#define WS_Z      (WS_H + 1536)              // 1536

typedef float v4f __attribute__((ext_vector_type(4)));

__device__ __forceinline__ float blk_sum4(float v, float* red, int lane, int wave) {
#pragma unroll
  for (int off = 32; off; off >>= 1) v += __shfl_xor(v, off);
  __syncthreads();
  if (lane == 0) red[wave] = v;
  __syncthreads();
  return red[0] + red[1] + red[2] + red[3];
}

// ---------------- prep: grid (4, 8); m<3 -> u vectors, m==3 -> ent partials ----------------
__global__ __launch_bounds__(256) void prep_kernel(
    const float* __restrict__ qrgb, const float* __restrict__ qnir, const float* __restrict__ qtir,
    const float* __restrict__ inw, const float* __restrict__ inb,
    const float* __restrict__ entw, const float* __restrict__ entb,
    float* __restrict__ ws)
{
  const int m = blockIdx.x, h = blockIdx.y;
  const int tid = threadIdx.x, lane = tid & 63, wave = tid >> 6;
  __shared__ float qvl[64];
  __shared__ float red[4];

  if (m == 3) {
    const float* base = entw + (size_t)h * 64 * 512;
    float acc0 = 0.f, acc1 = 0.f;
#pragma unroll 8
    for (int r = 0; r < 64; r++) {
      acc0 += base[(size_t)r * 512 + tid];
      acc1 += base[(size_t)r * 512 + tid + 256];
    }
    ws[WS_ENTP + h * 512 + tid] = acc0;
    ws[WS_ENTP + h * 512 + tid + 256] = acc1;
    return;
  }

  const float* qry = (m == 0) ? qrgb : (m == 1) ? qnir : qtir;
  float4 q0 = *(const float4*)(qry + 4 * lane);
  float4 q1 = *(const float4*)(qry + 256 + 4 * lane);
#pragma unroll 4
  for (int dd = 0; dd < 16; dd++) {
    const int d = wave * 16 + dd;
    const float* wr = inw + (size_t)(h * 64 + d) * 512;
    float4 w0 = *(const float4*)(wr + 4 * lane);
    float4 w1 = *(const float4*)(wr + 256 + 4 * lane);
    float p = w0.x * q0.x + w0.y * q0.y + w0.z * q0.z + w0.w * q0.w
            + w1.x * q1.x + w1.y * q1.y + w1.z * q1.z + w1.w * q1.w;
#pragma unroll
    for (int off = 32; off; off >>= 1) p += __shfl_xor(p, off);
    if (lane == 0) qvl[d] = p + inb[h * 64 + d];
  }
  __syncthreads();
  float acc0 = 0.f, acc1 = 0.f;
  const float* wk = inw + (size_t)(512 + h * 64) * 512;
#pragma unroll 8
  for (int d = 0; d < 64; d++) {
    float qq = qvl[d];
    acc0 = fmaf(qq, wk[(size_t)d * 512 + tid], acc0);
    acc1 = fmaf(qq, wk[(size_t)d * 512 + tid + 256], acc1);
  }
  ws[WS_U + m * 4096 + h * 512 + tid] = 0.125f * acc0;
  ws[WS_U + m * 4096 + h * 512 + tid + 256] = 0.125f * acc1;
  if (m == 0 && h == 0) {
    float v = entb[tid] + entb[tid + 256];
    float s = blk_sum4(v, red, lane, wave);
    if (tid == 0) ws[WS_ENTBM] = s * (1.f / 512.f);
  }
}

// ---------------- attn_pool: 4-row batched transpose-reduce online softmax ----------------
// Per 4-row batch: 32 partials/lane (4 rows x 8 heads); one generalized pair-merge
// butterfly (31 merges, masks 1/2/4/8/16, + xor32 add) fully reduces ALL 32 sums in a
// single 6-deep chain -> lane L holds score of (r_own, h_own). Group max over 4 rows
// (2 shuffles), deferred-max (thr 8, cold), ONE exp/lane, publish (w,scl) via 128B LDS.
// Accumulate 256 FMA from registers. Amortizes butterfly/LDS-roundtrip/exp/u-reload 4x
// vs the per-row scheme. m/s tracked as 2 regs (per-lane, own head). Row 128 = masked
// epilogue batch (scores -> -3e38 => w=0).
__global__ __launch_bounds__(256, 2) void attn_pool_kernel(
    const float* __restrict__ trgb, const float* __restrict__ tnir, const float* __restrict__ ttir,
    const float* __restrict__ ws, float* __restrict__ Pout)
{
  const int b = blockIdx.x, m = blockIdx.y;
  const int tid = threadIdx.x, lane = tid & 63, wave = tid >> 6;
  const float* tok = ((m == 0) ? trgb : (m == 1) ? tnir : ttir) + (size_t)b * 129 * 512;
  const float* u = ws + WS_U + m * 4096;

  __shared__ float lacc[4][2][512];   // 16 KB combine stage (2 heads / round)
  __shared__ float lstat[4][16];      // per-wave m[8], s[8]
  __shared__ float wls[4][32];        // per-wave w[r*8+h] publish
  __shared__ float sls[4][8];         // per-wave scl[h] publish

  const int b0 = lane & 1, b1 = (lane >> 1) & 1, b2 = (lane >> 2) & 1;
  const int b3 = (lane >> 3) & 1, b4 = (lane >> 4) & 1;
  const int r_own = (b0 << 1) | b1;                     // row-in-batch this lane owns
  const int h_own = (b2 << 2) | (b3 << 1) | b4;         // head this lane owns

  float acc[8][8];                    // [head][col: 4*lane.. / 256+4*lane..]
#pragma unroll
  for (int h = 0; h < 8; h++)
#pragma unroll
    for (int j = 0; j < 8; j++) acc[h][j] = 0.f;
  float m_own = 0.f, s_own = 0.f;

  const int rbase = wave * 32;
  v4f curA[4], curC[4], nxtA[4], nxtC[4];

  auto loadbatch = [&](int row0, v4f (&A)[4], v4f (&C)[4]) {
#pragma unroll
    for (int r = 0; r < 4; r++) {
      int rr = row0 + r; rr = (rr > 128) ? 128 : rr;    // clamp for tail batch
      const float* rp = tok + (size_t)rr * 512;
      A[r] = *(const v4f*)(rp + 4 * lane);
      C[r] = *(const v4f*)(rp + 256 + 4 * lane);
    }
  };

  // body: process batch in (pA,pC); optionally prefetch nextRow0 into (fA,fC)
  auto body = [&](v4f (&pA)[4], v4f (&pC)[4], v4f (&fA)[4], v4f (&fC)[4],
                  int nextRow0, bool maskTail) {
    // ---- dots: 32 partials (u re-loaded per batch, L1-hot, amortized 4x) ----
    float x[32];
#pragma unroll
    for (int h = 0; h < 8; h++) {
      v4f U0 = *(const v4f*)(u + h * 512 + 4 * lane);
      v4f U1 = *(const v4f*)(u + h * 512 + 256 + 4 * lane);
#pragma unroll
      for (int r = 0; r < 4; r++) {
        x[r * 8 + h] = pA[r][0] * U0[0] + pA[r][1] * U0[1] + pA[r][2] * U0[2] + pA[r][3] * U0[3]
                     + pC[r][0] * U1[0] + pC[r][1] * U1[1] + pC[r][2] * U1[2] + pC[r][3] * U1[3];
      }
    }
    // ---- transpose-reduce: 31 merges + final xor32 (one 6-deep chain / 4 rows) ----
#define MERGE_STAGE(n, M, bit)                                  \
    _Pragma("unroll")                                           \
    for (int j = 0; j < (n) / 2; j++) {                         \
      float keep = (bit) ? x[j + (n) / 2] : x[j];               \
      float send = (bit) ? x[j] : x[j + (n) / 2];               \
      x[j] = keep + __shfl_xor(send, (M));                      \
    }
    MERGE_STAGE(32, 1, b0)
    MERGE_STAGE(16, 2, b1)
    MERGE_STAGE(8, 4, b2)
    MERGE_STAGE(4, 8, b3)
    MERGE_STAGE(2, 16, b4)
#undef MERGE_STAGE
    float T = x[0] + __shfl_xor(x[0], 32);   // full 64-lane sum; (r_own,h_own) per lane
    if (maskTail && r_own != 0) T = -3.0e38f;  // only row 128 valid in tail batch
    // ---- per-head batch max over 4 rows (rows vary with lane bits 0,1) ----
    float mb = fmaxf(T, __shfl_xor(T, 1));
    mb = fmaxf(mb, __shfl_xor(mb, 2));
    // ---- owner math (uniform within head group) ----
    bool re = (mb > m_own + 8.f);            // deferred rescale, cold
    float scl = __expf(re ? (m_own - mb) : 0.f);   // exp(0)=1 on hot path
    float mN = re ? mb : m_own;
    float w = __expf(T - mN);                // ONE exp per lane per batch
    float sb = w + __shfl_xor(w, 1);
    sb += __shfl_xor(sb, 2);
    s_own = s_own * scl + sb;
    m_own = mN;
    // ---- publish (lanes 0-31 hold the 32 distinct (r,h) values) ----
    if (lane < 32) {
      wls[wave][r_own * 8 + h_own] = w;
      if ((lane & 3) == 0) sls[wave][h_own] = scl;
    }
    // ---- prefetch next batch (overlaps with accumulate below) ----
    if (nextRow0 >= 0) loadbatch(nextRow0, fA, fC);
    // ---- read publishes; cold rescale; accumulate ----
    float4 sc0 = *(const float4*)&sls[wave][0];
    float4 sc1 = *(const float4*)&sls[wave][4];
    float smin = fminf(fminf(fminf(sc0.x, sc0.y), fminf(sc0.z, sc0.w)),
                       fminf(fminf(sc1.x, sc1.y), fminf(sc1.z, sc1.w)));
    if (smin < 1.f) {                        // cold, wave-uniform
      float sv[8] = {sc0.x, sc0.y, sc0.z, sc0.w, sc1.x, sc1.y, sc1.z, sc1.w};
#pragma unroll
      for (int h = 0; h < 8; h++)
#pragma unroll
        for (int j = 0; j < 8; j++) acc[h][j] *= sv[h];
    }
#pragma unroll
    for (int r = 0; r < 4; r++) {
      float4 wlo = *(const float4*)&wls[wave][r * 8];
      float4 whi = *(const float4*)&wls[wave][r * 8 + 4];
      float wv[8] = {wlo.x, wlo.y, wlo.z, wlo.w, whi.x, whi.y, whi.z, whi.w};
#pragma unroll
      for (int h = 0; h < 8; h++) {
        acc[h][0] = fmaf(wv[h], pA[r][0], acc[h][0]);
        acc[h][1] = fmaf(wv[h], pA[r][1], acc[h][1]);
        acc[h][2] = fmaf(wv[h], pA[r][2], acc[h][2]);
        acc[h][3] = fmaf(wv[h], pA[r][3], acc[h][3]);
        acc[h][4] = fmaf(wv[h], pC[r][0], acc[h][4]);
        acc[h][5] = fmaf(wv[h], pC[r][1], acc[h][5]);
        acc[h][6] = fmaf(wv[h], pC[r][2], acc[h][6]);
        acc[h][7] = fmaf(wv[h], pC[r][3], acc[h][7]);
      }
    }
  };

  loadbatch(rbase, curA, curC);
  for (int bt2 = 0; bt2 < 4; bt2++) {
    body(curA, curC, nxtA, nxtC, rbase + 8 * bt2 + 4, false);
    int nr2 = (bt2 < 3) ? (rbase + 8 * bt2 + 8) : ((wave == 0) ? 128 : -1);
    body(nxtA, nxtC, curA, curC, nr2, false);
  }
  if (wave == 0) body(curA, curC, nxtA, nxtC, -1, true);  // masked row-128 batch

  // ---- cross-wave combine ----
  if (lane < 32 && (lane & 3) == 0) {
    lstat[wave][h_own] = m_own;
    lstat[wave][8 + h_own] = s_own;
  }
  __syncthreads();
  float fw[4][8];
#pragma unroll
  for (int h = 0; h < 8; h++) {
    float m0 = lstat[0][h], m1 = lstat[1][h], m2 = lstat[2][h], m3 = lstat[3][h];
    float Mx = fmaxf(fmaxf(m0, m1), fmaxf(m2, m3));
    float f0 = __expf(m0 - Mx), f1 = __expf(m1 - Mx);
    float f2 = __expf(m2 - Mx), f3 = __expf(m3 - Mx);
    float S = lstat[0][8 + h] * f0 + lstat[1][8 + h] * f1
            + lstat[2][8 + h] * f2 + lstat[3][8 + h] * f3;
    float is = 1.f / S;
    fw[0][h] = f0 * is; fw[1][h] = f1 * is; fw[2][h] = f2 * is; fw[3][h] = f3 * is;
  }
  float* po = Pout + (size_t)(m * 512 + b) * 4096 + 2 * tid;
#pragma unroll
  for (int hb = 0; hb < 8; hb += 2) {
    if (hb) __syncthreads();          // previous round's reads done before reuse
#pragma unroll
    for (int hh = 0; hh < 2; hh++) {
      const int h = hb + hh;
      *(float4*)&lacc[wave][hh][4 * lane] =
          make_float4(acc[h][0], acc[h][1], acc[h][2], acc[h][3]);
      *(float4*)&lacc[wave][hh][256 + 4 * lane] =
          make_float4(acc[h][4], acc[h][5], acc[h][6], acc[h][7]);
    }
    __syncthreads();
#pragma unroll
    for (int hh = 0; hh < 2; hh++) {
      const int h = hb + hh;
      float2 x0 = *(const float2*)&lacc[0][hh][2 * tid];
      float2 x1 = *(const float2*)&lacc[1][hh][2 * tid];
      float2 x2 = *(const float2*)&lacc[2][hh][2 * tid];
      float2 x3 = *(const float2*)&lacc[3][hh][2 * tid];
      float ox = x0.x * fw[0][h] + x1.x * fw[1][h] + x2.x * fw[2][h] + x3.x * fw[3][h];
      float oy = x0.y * fw[0][h] + x1.y * fw[1][h] + x2.y * fw[2][h] + x3.y * fw[3][h];
      *(float2*)(po + h * 512) = make_float2(ox, oy);
    }
  }
}

// ---------------- f32 GEMM: C = A @ B^T (+bias), 64x64 tile, 4x4 micro ----------------
__global__ __launch_bounds__(256) void gemm_bt_kernel(
    const float* __restrict__ A, const float* __restrict__ B,
    const float* __restrict__ bias, float* __restrict__ C,
    int K, int lda, int ldb, int ldc,
    long sA, long sB, long sC, int sBias, int addBias)
{
  A += (long)blockIdx.z * sA;
  B += (long)blockIdx.z * sB;
  C += (long)blockIdx.z * sC;
  const float* bp = bias + (long)blockIdx.z * sBias;
  __shared__ float As[32][68];
  __shared__ float Bs[32][68];
  const int tid = threadIdx.x;
  const int tx = tid & 15, ty = tid >> 4;
  const int rowL = tid >> 3;
  const int colv = (tid & 7) << 2;
  const int m0 = blockIdx.x * 64, n0 = blockIdx.y * 64;
  float acc[4][4] = {};
  for (int k0 = 0; k0 < K; k0 += 32) {
#pragma unroll
    for (int it = 0; it < 2; it++) {
      const int r = rowL + it * 32;
      float4 v = *(const float4*)(A + (size_t)(m0 + r) * lda + k0 + colv);
      As[colv + 0][r] = v.x; As[colv + 1][r] = v.y; As[colv + 2][r] = v.z; As[colv + 3][r] = v.w;
      float4 w = *(const float4*)(B + (size_t)(n0 + r) * ldb + k0 + colv);
      Bs[colv + 0][r] = w.x; Bs[colv + 1][r] = w.y; Bs[colv + 2][r] = w.z; Bs[colv + 3][r] = w.w;
    }
    __syncthreads();
#pragma unroll
    for (int k = 0; k < 32; k++) {
      float4 a4 = *(const float4*)&As[k][ty * 4];
      float4 b4 = *(const float4*)&Bs[k][tx * 4];
      acc[0][0] += a4.x * b4.x; acc[0][1] += a4.x * b4.y; acc[0][2] += a4.x * b4.z; acc[0][3] += a4.x * b4.w;
      acc[1][0] += a4.y * b4.x; acc[1][1] += a4.y * b4.y; acc[1][2] += a4.y * b4.z; acc[1][3] += a4.y * b4.w;
      acc[2][0] += a4.z * b4.x; acc[2][1] += a4.z * b4.y; acc[2][2] += a4.z * b4.z; acc[2][3] += a4.z * b4.w;
      acc[3][0] += a4.w * b4.x; acc[3][1] += a4.w * b4.y; acc[3][2] += a4.w * b4.z; acc[3][3] += a4.w * b4.w;
    }
    __syncthreads();
  }
  float4 bv = make_float4(0.f, 0.f, 0.f, 0.f);
  if (addBias) bv = *(const float4*)(bp + n0 + tx * 4);
#pragma unroll
  for (int i = 0; i < 4; i++) {
    float4 o;
    o.x = acc[i][0] + bv.x; o.y = acc[i][1] + bv.y;
    o.z = acc[i][2] + bv.z; o.w = acc[i][3] + bv.w;
    *(float4*)(C + (size_t)(m0 + ty * 4 + i) * ldc + n0 + tx * 4) = o;
  }
}

// ---------------- LN(attn out) + entropy + z ----------------
__global__ __launch_bounds__(256) void ln_ent_kernel(
    const float* __restrict__ out2,
    const float* __restrict__ lng, const float* __restrict__ lnb,
    const float* __restrict__ ws, float* __restrict__ hcat,
    float* __restrict__ Hout, float* __restrict__ zout)
{
  const int r = blockIdx.x;
  const int mod = r >> 9, b = r & 511;
  const int tid = threadIdx.x, lane = tid & 63, wave = tid >> 6;
  __shared__ float red[4];
  const float* x = out2 + (size_t)r * 512;
  float2 v = *(const float2*)(x + 2 * tid);
  float s = blk_sum4(v.x + v.y, red, lane, wave);
  float sq = blk_sum4(v.x * v.x + v.y * v.y, red, lane, wave);
  float mean = s * (1.f / 512.f);
  float var = sq * (1.f / 512.f) - mean * mean;
  float rstd = rsqrtf(var + 1e-5f);
  float2 g = *(const float2*)(lng + 2 * tid);
  float2 bb = *(const float2*)(lnb + 2 * tid);
  float h0 = (v.x - mean) * rstd * g.x + bb.x;
  float h1 = (v.y - mean) * rstd * g.y + bb.y;
  *(float2*)(hcat + (size_t)b * 1536 + mod * 512 + 2 * tid) = make_float2(h0, h1);
  float2 ep = make_float2(0.f, 0.f);
#pragma unroll
  for (int j = 0; j < 8; j++) {
    float2 t = *(const float2*)(ws + WS_ENTP + j * 512 + 2 * tid);
    ep.x += t.x; ep.y += t.y;
  }
  ep.x *= (1.f / 512.f); ep.y *= (1.f / 512.f);
  float fa0 = fabsf(h0) + 1e-8f, fa1 = fabsf(h1) + 1e-8f;
  float S = blk_sum4(fa0 + fa1, red, lane, wave);
  float zz = blk_sum4(h0 * ep.x + h1 * ep.y, red, lane, wave);
  float invS = 1.f / S;
  float p0 = fa0 * invS, p1 = fa1 * invS;
  float t = blk_sum4(p0 * logf(p0 + 1e-8f) + p1 * logf(p1 + 1e-8f), red, lane, wave);
  if (tid == 0) {
    Hout[mod * 512 + b] = -t;
    zout[mod * 512 + b] = zz + ws[WS_ENTBM];
  }
}

// ---------------- gate LN/relu/sigmoid + entropy softmax + fuse ----------------
__global__ __launch_bounds__(256) void gate_fuse_kernel(
    const float* __restrict__ gpre, const float* __restrict__ glng, const float* __restrict__ glnb,
    const float* __restrict__ gw2, const float* __restrict__ gb2, const float* __restrict__ gb1,
    const float* __restrict__ araw, const float* __restrict__ hcat,
    const float* __restrict__ H, const float* __restrict__ z,
    float* __restrict__ hfused)
{
  const int b = blockIdx.x;
  const int tid = threadIdx.x, lane = tid & 63, wave = tid >> 6;
  __shared__ float red[4];
  float2 v;
  {
    float2 p0 = *(const float2*)(gpre + (size_t)b * 512 + 2 * tid);
    float2 p1 = *(const float2*)(gpre + 262144 + (size_t)b * 512 + 2 * tid);
    float2 p2 = *(const float2*)(gpre + 524288 + (size_t)b * 512 + 2 * tid);
    float2 bi = *(const float2*)(gb1 + 2 * tid);
    v.x = p0.x + p1.x + p2.x + bi.x;
    v.y = p0.y + p1.y + p2.y + bi.y;
  }
  float s = blk_sum4(v.x + v.y, red, lane, wave);
  float sq = blk_sum4(v.x * v.x + v.y * v.y, red, lane, wave);
  float mean = s * (1.f / 512.f), var = sq * (1.f / 512.f) - mean * mean;
  float rstd = rsqrtf(var + 1e-5f);
  float2 g = *(const float2*)(glng + 2 * tid);
  float2 bb = *(const float2*)(glnb + 2 * tid);
  float g0 = fmaxf((v.x - mean) * rstd * g.x + bb.x, 0.f);
  float g1 = fmaxf((v.y - mean) * rstd * g.y + bb.y, 0.f);
  float d0 = blk_sum4(g0 * gw2[2 * tid] + g1 * gw2[2 * tid + 1], red, lane, wave);
  float d1 = blk_sum4(g0 * gw2[512 + 2 * tid] + g1 * gw2[512 + 2 * tid + 1], red, lane, wave);
  float d2 = blk_sum4(g0 * gw2[1024 + 2 * tid] + g1 * gw2[1024 + 2 * tid + 1], red, lane, wave);
  float ga0 = 1.f / (1.f + __expf(-(d0 + gb2[0])));
  float ga1 = 1.f / (1.f + __expf(-(d1 + gb2[1])));
  float ga2 = 1.f / (1.f + __expf(-(d2 + gb2[2])));
  float sc0 = z[b] * __expf(-H[b]);
  float sc1 = z[512 + b] * __expf(-H[512 + b]);
  float sc2 = z[1024 + b] * __expf(-H[1024 + b]);
  float mxs = fmaxf(sc0, fmaxf(sc1, sc2));
  float e0 = __expf(sc0 - mxs), e1 = __expf(sc1 - mxs), e2 = __expf(sc2 - mxs);
  float inv = 1.f / (e0 + e1 + e2);
  e0 *= inv; e1 *= inv; e2 *= inv;
  float alpha = 1.f / (1.f + __expf(-araw[0]));
  const float* hb = hcat + (size_t)b * 1536 + 2 * tid;
  float2 hr = *(const float2*)hb;
  float2 hn = *(const float2*)(hb + 512);
  float2 ht = *(const float2*)(hb + 1024);
  float2 o;
  o.x = alpha * (e0 * hr.x + e1 * hn.x + e2 * ht.x)
      + (1.f - alpha) * (ga0 * hr.x + ga1 * hn.x + ga2 * ht.x);
  o.y = alpha * (e0 * hr.y + e1 * hn.y + e2 * ht.y)
      + (1.f - alpha) * (ga0 * hr.y + ga1 * hn.y + ga2 * ht.y);
  *(float2*)(hfused + (size_t)b * 512 + 2 * tid) = o;
}

// ---------------- final LN(enh) + concat-add ----------------
__global__ __launch_bounds__(256) void final_out_kernel(
    const float* __restrict__ epre, const float* __restrict__ enb,
    const float* __restrict__ elng, const float* __restrict__ elnb,
    const float* __restrict__ hcat, float* __restrict__ out)
{
  const int b = blockIdx.x;
  const int tid = threadIdx.x, lane = tid & 63, wave = tid >> 6;
  __shared__ float red[4];
  float2 v;
  {
    float2 p0 = *(const float2*)(epre + (size_t)b * 512 + 2 * tid);
    float2 p1 = *(const float2*)(epre + 262144 + (size_t)b * 512 + 2 * tid);
    float2 bi = *(const float2*)(enb + 2 * tid);
    v.x = p0.x + p1.x + bi.x;
    v.y = p0.y + p1.y + bi.y;
  }
  float s = blk_sum4(v.x + v.y, red, lane, wave);
  float sq = blk_sum4(v.x * v.x + v.y * v.y, red, lane, wave);
  float mean = s * (1.f / 512.f), var = sq * (1.f / 512.f) - mean * mean;
  float rstd = rsqrtf(var + 1e-5f);
  float2 g = *(const float2*)(elng + 2 * tid);
  float2 bb = *(const float2*)(elnb + 2 * tid);
  float e0 = (v.x - mean) * rstd * g.x + bb.x;
  float e1 = (v.y - mean) * rstd * g.y + bb.y;
  const float* hb = hcat + (size_t)b * 1536 + 2 * tid;
  float* ob = out + (size_t)b * 1536 + 2 * tid;
#pragma unroll
  for (int mm = 0; mm < 3; mm++) {
    float2 hv = *(const float2*)(hb + mm * 512);
    *(float2*)(ob + mm * 512) = make_float2(hv.x + e0, hv.y + e1);
  }
}

extern "C" void kernel_launch(void* const* d_in, const int* in_sizes, int n_in,
                              void* d_out, int out_size, void* d_ws, size_t ws_size,
                              hipStream_t stream)
{
  const float* trgb = (const float*)d_in[0];
  const float* tnir = (const float*)d_in[1];
  const float* ttir = (const float*)d_in[2];
  const float* qrgb = (const float*)d_in[3];
  const float* qnir = (const float*)d_in[4];
  const float* qtir = (const float*)d_in[5];
  const float* inw  = (const float*)d_in[6];
  const float* inb  = (const float*)d_in[7];
  const float* outw = (const float*)d_in[8];
  const float* outb = (const float*)d_in[9];
  const float* alng = (const float*)d_in[10];
  const float* alnb = (const float*)d_in[11];
  const float* entw = (const float*)d_in[12];
  const float* entb = (const float*)d_in[13];
  const float* gw1  = (const float*)d_in[14];
  const float* gb1  = (const float*)d_in[15];
  const float* glng = (const float*)d_in[16];
  const float* glnb = (const float*)d_in[17];
  const float* gw2  = (const float*)d_in[18];
  const float* gb2  = (const float*)d_in[19];
  const float* araw = (const float*)d_in[20];
  const float* enw  = (const float*)d_in[21];
  const float* enb  = (const float*)d_in[22];
  const float* elng = (const float*)d_in[23];
  const float* elnb = (const float*)d_in[24];
  float* ws = (float*)d_ws;
  float* out = (float*)d_out;

  hipLaunchKernelGGL(prep_kernel, dim3(4, 8), dim3(256), 0, stream,
                     qrgb, qnir, qtir, inw, inb, entw, entb, ws);
  hipLaunchKernelGGL(attn_pool_kernel, dim3(512, 3), dim3(256), 0, stream,
                     trgb, tnir, ttir, ws, ws + WS_P);
  // vout = P @ Wv^T + bv (batched over 8 heads)
  hipLaunchKernelGGL(gemm_bt_kernel, dim3(24, 1, 8), dim3(256), 0, stream,
                     ws + WS_P, inw + (size_t)1024 * 512, inb + 1024, ws + WS_VOUT,
                     512, 4096, 512, 512,
                     (long)512, (long)64 * 512, (long)64, 64, 1);
  // out2 = vout @ Wo^T + bo
  hipLaunchKernelGGL(gemm_bt_kernel, dim3(24, 8, 1), dim3(256), 0, stream,
                     ws + WS_VOUT, outw, outb, ws + WS_OUT2,
                     512, 512, 512, 512, 0L, 0L, 0L, 0, 1);
  hipLaunchKernelGGL(ln_ent_kernel, dim3(1536), dim3(256), 0, stream,
                     ws + WS_OUT2, alng, alnb, ws, ws + WS_HCAT, ws + WS_H, ws + WS_Z);
  // g_pre partials = hcat @ gate_w1^T (split-K x3, bias added in gate_fuse)
  hipLaunchKernelGGL(gemm_bt_kernel, dim3(8, 8, 3), dim3(256), 0, stream,
                     ws + WS_HCAT, gw1, gb1, ws + WS_GPRE,
                     512, 1536, 1536, 512,
                     (long)512, (long)512, (long)262144, 0, 0);
  hipLaunchKernelGGL(gate_fuse_kernel, dim3(512), dim3(256), 0, stream,
                     ws + WS_GPRE, glng, glnb, gw2, gb2, gb1, araw,
                     ws + WS_HCAT, ws + WS_H, ws + WS_Z, ws + WS_HFUSED);
  // enh partials = h_fused @ enh_w^T (split-K x2, bias added in final_out)
  hipLaunchKernelGGL(gemm_bt_kernel, dim3(8, 8, 2), dim3(256), 0, stream,
                     ws + WS_HFUSED, enw, enb, ws + WS_ENHPRE,
                     256, 512, 512, 512,
                     (long)256, (long)256, (long)262144, 0, 0);
  hipLaunchKernelGGL(final_out_kernel, dim3(512), dim3(256), 0, stream,
                     ws + WS_ENHPRE, enb, elng, elnb, ws + WS_HCAT, out);
}

// Round 5
// 369.259 us; speedup vs baseline: 2.9187x; 1.2076x over previous
//
#include <hip/hip_runtime.h>
#include <cstdint>

// ---------------- workspace layout (float offsets) ----------------
#define WS_U      0                          // 3*8*512 = 12288
#define WS_C0     12288                      // 24 (unused now)
#define WS_ENTBM  12312                      // 1
#define WS_ENTP   12320                      // 8*512 = 4096
#define WS_P      16416                      // 1536*4096 = 6291456
#define WS_OUT2   WS_P                       // alias (P dead after vout GEMM)
#define WS_GPRE   (WS_P + 786432)            // 3 partials * 262144
#define WS_HFUSED (WS_P + 1572864)           // 262144
#define WS_ENHPRE (WS_P + 1835008)           // 2 partials * 262144
#define WS_VOUT   (WS_P + 6291456)           // 786432
#define WS_HCAT   (WS_VOUT + 786432)         // 786432
#define WS_H      (WS_HCAT + 786432)         // 1536
#define WS_Z      (WS_H + 1536)              // 1536

__device__ __forceinline__ float blk_sum4(float v, float* red, int lane, int wave) {
#pragma unroll
  for (int off = 32; off; off >>= 1) v += __shfl_xor(v, off);
  __syncthreads();
  if (lane == 0) red[wave] = v;
  __syncthreads();
  return red[0] + red[1] + red[2] + red[3];
}

// ---------------- prep: grid (4, 8); m<3 -> u vectors, m==3 -> ent partials ----------------
__global__ __launch_bounds__(256) void prep_kernel(
    const float* __restrict__ qrgb, const float* __restrict__ qnir, const float* __restrict__ qtir,
    const float* __restrict__ inw, const float* __restrict__ inb,
    const float* __restrict__ entw, const float* __restrict__ entb,
    float* __restrict__ ws)
{
  const int m = blockIdx.x, h = blockIdx.y;
  const int tid = threadIdx.x, lane = tid & 63, wave = tid >> 6;
  __shared__ float qvl[64];
  __shared__ float red[4];

  if (m == 3) {
    const float* base = entw + (size_t)h * 64 * 512;
    float acc0 = 0.f, acc1 = 0.f;
#pragma unroll 8
    for (int r = 0; r < 64; r++) {
      acc0 += base[(size_t)r * 512 + tid];
      acc1 += base[(size_t)r * 512 + tid + 256];
    }
    ws[WS_ENTP + h * 512 + tid] = acc0;
    ws[WS_ENTP + h * 512 + tid + 256] = acc1;
    return;
  }

  const float* qry = (m == 0) ? qrgb : (m == 1) ? qnir : qtir;
  float4 q0 = *(const float4*)(qry + 4 * lane);
  float4 q1 = *(const float4*)(qry + 256 + 4 * lane);
#pragma unroll 4
  for (int dd = 0; dd < 16; dd++) {
    const int d = wave * 16 + dd;
    const float* wr = inw + (size_t)(h * 64 + d) * 512;
    float4 w0 = *(const float4*)(wr + 4 * lane);
    float4 w1 = *(const float4*)(wr + 256 + 4 * lane);
    float p = w0.x * q0.x + w0.y * q0.y + w0.z * q0.z + w0.w * q0.w
            + w1.x * q1.x + w1.y * q1.y + w1.z * q1.z + w1.w * q1.w;
#pragma unroll
    for (int off = 32; off; off >>= 1) p += __shfl_xor(p, off);
    if (lane == 0) qvl[d] = p + inb[h * 64 + d];
  }
  __syncthreads();
  float acc0 = 0.f, acc1 = 0.f;
  const float* wk = inw + (size_t)(512 + h * 64) * 512;
#pragma unroll 8
  for (int d = 0; d < 64; d++) {
    float qq = qvl[d];
    acc0 = fmaf(qq, wk[(size_t)d * 512 + tid], acc0);
    acc1 = fmaf(qq, wk[(size_t)d * 512 + tid + 256], acc1);
  }
  ws[WS_U + m * 4096 + h * 512 + tid] = 0.125f * acc0;
  ws[WS_U + m * 4096 + h * 512 + tid + 256] = 0.125f * acc1;
  if (m == 0 && h == 0) {
    float v = entb[tid] + entb[tid + 256];
    float s = blk_sum4(v, red, lane, wave);
    if (tid == 0) ws[WS_ENTBM] = s * (1.f / 512.f);
  }
}

// ---------------- attn_pool: single-pass online softmax ----------------
// Round-1 body (spill-free: float4 by value, scalar owner state) with:
//  (a) lacc[4][2][512] (16KB): LDS occupancy limit 33->17 KB (R3-validated lever)
//  (b) owner-side exp: owning lane applies deferred-max + exp BEFORE the LDS
//      publish (w,m); hot-path readers do no exp.
//  NO __launch_bounds__ 2nd arg (R3/R4: any cap forces catastrophic spill).
__global__ __launch_bounds__(256) void attn_pool_kernel(
    const float* __restrict__ trgb, const float* __restrict__ tnir, const float* __restrict__ ttir,
    const float* __restrict__ ws, float* __restrict__ Pout)
{
  const int b = blockIdx.x, m = blockIdx.y;
  const int tid = threadIdx.x, lane = tid & 63, wave = tid >> 6;
  const float* tok = ((m == 0) ? trgb : (m == 1) ? tnir : ttir) + (size_t)b * 129 * 512;
  const float* u = ws + WS_U + m * 4096;

  __shared__ float lacc[4][2][512];   // 16 KB combine stage (2 heads / round)
  __shared__ float lstat[4][16];      // per-wave m[8], s[8]
  __shared__ float2 tsh2[4][8];       // per-row (w, m) per head

  float4 u0[8], u1[8];
#pragma unroll
  for (int h = 0; h < 8; h++) {
    u0[h] = *(const float4*)(u + h * 512 + 4 * lane);
    u1[h] = *(const float4*)(u + h * 512 + 256 + 4 * lane);
  }
  const int s0 = lane & 1, s1 = (lane >> 1) & 1, s2 = (lane >> 2) & 1;
  const int hidx = ((lane & 1) << 2) | (lane & 2) | ((lane >> 2) & 1);

  float acc[8][8];                    // [head][col: 4*lane.. / 256+4*lane..]
  float mh[8], sh[8];
#pragma unroll
  for (int h = 0; h < 8; h++) {
    mh[h] = 0.f; sh[h] = 0.f;
#pragma unroll
    for (int j = 0; j < 8; j++) acc[h][j] = 0.f;
  }

  auto process_row = [&](const float4 a, const float4 c) {
    float p[8];
#pragma unroll
    for (int h = 0; h < 8; h++)
      p[h] = a.x * u0[h].x + a.y * u0[h].y + a.z * u0[h].z + a.w * u0[h].w
           + c.x * u1[h].x + c.y * u1[h].y + c.z * u1[h].z + c.w * u1[h].w;
    // pair-merge head-distributing reduce: after xor4 each lane holds one head;
    // xor8/16/32 complete the 64-lane sum leaving EVERY lane with head hidx's total.
    float q0 = (s0 ? p[4] : p[0]) + __shfl_xor(s0 ? p[0] : p[4], 1);
    float q1 = (s0 ? p[5] : p[1]) + __shfl_xor(s0 ? p[1] : p[5], 1);
    float q2 = (s0 ? p[6] : p[2]) + __shfl_xor(s0 ? p[2] : p[6], 1);
    float q3 = (s0 ? p[7] : p[3]) + __shfl_xor(s0 ? p[3] : p[7], 1);
    float r0 = (s1 ? q2 : q0) + __shfl_xor(s1 ? q0 : q2, 2);
    float r1 = (s1 ? q3 : q1) + __shfl_xor(s1 ? q1 : q3, 2);
    float t  = (s2 ? r1 : r0) + __shfl_xor(s2 ? r0 : r1, 4);
    t += __shfl_xor(t, 8);
    t += __shfl_xor(t, 16);
    t += __shfl_xor(t, 32);
    // owner-side deferred-max + exp for head hidx (threshold 8; cold path uniform)
    float msel = s0 ? (s1 ? (s2 ? mh[7] : mh[6]) : (s2 ? mh[5] : mh[4]))
                    : (s1 ? (s2 ? mh[3] : mh[2]) : (s2 ? mh[1] : mh[0]));
    float mA = (t > msel + 8.f) ? t : msel;
    float wo = __expf(t - mA);
    if (lane < 8) tsh2[wave][hidx] = make_float2(wo, mA);
    // hot path: one b64 broadcast per head, no exp
#pragma unroll
    for (int h = 0; h < 8; h++) {
      float2 wm = tsh2[wave][h];
      if (wm.y > mh[h]) {               // cold, uniform across lanes
        float scl = __expf(mh[h] - wm.y);
        sh[h] *= scl;
#pragma unroll
        for (int j = 0; j < 8; j++) acc[h][j] *= scl;
        mh[h] = wm.y;
      }
      float w = wm.x;
      sh[h] += w;
      acc[h][0] = fmaf(w, a.x, acc[h][0]);
      acc[h][1] = fmaf(w, a.y, acc[h][1]);
      acc[h][2] = fmaf(w, a.z, acc[h][2]);
      acc[h][3] = fmaf(w, a.w, acc[h][3]);
      acc[h][4] = fmaf(w, c.x, acc[h][4]);
      acc[h][5] = fmaf(w, c.y, acc[h][5]);
      acc[h][6] = fmaf(w, c.z, acc[h][6]);
      acc[h][7] = fmaf(w, c.w, acc[h][7]);
    }
  };

  // rows l = wave + 4*i; wave 0 gets 33 rows (incl. 128), waves 1-3 get 32
  const int nrows = (wave == 0) ? 33 : 32;
  const float* r0p = tok + (size_t)wave * 512;
  float4 a0 = *(const float4*)(r0p + 4 * lane);
  float4 c0 = *(const float4*)(r0p + 256 + 4 * lane);
  const float* r1p = tok + (size_t)(wave + 4) * 512;
  float4 a1 = *(const float4*)(r1p + 4 * lane);
  float4 c1 = *(const float4*)(r1p + 256 + 4 * lane);
  for (int i = 0; i + 2 < nrows; i++) {
    const float* np = tok + (size_t)(wave + 4 * (i + 2)) * 512;
    float4 na = *(const float4*)(np + 4 * lane);
    float4 nc = *(const float4*)(np + 256 + 4 * lane);
    process_row(a0, c0);
    a0 = a1; c0 = c1;
    a1 = na; c1 = nc;
  }
  process_row(a0, c0);
  process_row(a1, c1);

  // ---- cross-wave combine ----
  if (lane == 0) {
#pragma unroll
    for (int h = 0; h < 8; h++) {
      lstat[wave][h] = mh[h];
      lstat[wave][8 + h] = sh[h];
    }
  }
  __syncthreads();
  float fw[4][8];
#pragma unroll
  for (int h = 0; h < 8; h++) {
    float m0 = lstat[0][h], m1 = lstat[1][h], m2 = lstat[2][h], m3 = lstat[3][h];
    float Mx = fmaxf(fmaxf(m0, m1), fmaxf(m2, m3));
    float f0 = __expf(m0 - Mx), f1 = __expf(m1 - Mx);
    float f2 = __expf(m2 - Mx), f3 = __expf(m3 - Mx);
    float S = lstat[0][8 + h] * f0 + lstat[1][8 + h] * f1
            + lstat[2][8 + h] * f2 + lstat[3][8 + h] * f3;
    float is = 1.f / S;
    fw[0][h] = f0 * is; fw[1][h] = f1 * is; fw[2][h] = f2 * is; fw[3][h] = f3 * is;
  }
  float* po = Pout + (size_t)(m * 512 + b) * 4096 + 2 * tid;
#pragma unroll
  for (int hb = 0; hb < 8; hb += 2) {
    if (hb) __syncthreads();          // previous round's reads done before reuse
#pragma unroll
    for (int hh = 0; hh < 2; hh++) {
      const int h = hb + hh;
      *(float4*)&lacc[wave][hh][4 * lane] =
          make_float4(acc[h][0], acc[h][1], acc[h][2], acc[h][3]);
      *(float4*)&lacc[wave][hh][256 + 4 * lane] =
          make_float4(acc[h][4], acc[h][5], acc[h][6], acc[h][7]);
    }
    __syncthreads();
#pragma unroll
    for (int hh = 0; hh < 2; hh++) {
      const int h = hb + hh;
      float2 x0 = *(const float2*)&lacc[0][hh][2 * tid];
      float2 x1 = *(const float2*)&lacc[1][hh][2 * tid];
      float2 x2 = *(const float2*)&lacc[2][hh][2 * tid];
      float2 x3 = *(const float2*)&lacc[3][hh][2 * tid];
      float ox = x0.x * fw[0][h] + x1.x * fw[1][h] + x2.x * fw[2][h] + x3.x * fw[3][h];
      float oy = x0.y * fw[0][h] + x1.y * fw[1][h] + x2.y * fw[2][h] + x3.y * fw[3][h];
      *(float2*)(po + h * 512) = make_float2(ox, oy);
    }
  }
}

// ---------------- f32 GEMM: C = A @ B^T (+bias), 64x64 tile, 4x4 micro ----------------
__global__ __launch_bounds__(256) void gemm_bt_kernel(
    const float* __restrict__ A, const float* __restrict__ B,
    const float* __restrict__ bias, float* __restrict__ C,
    int K, int lda, int ldb, int ldc,
    long sA, long sB, long sC, int sBias, int addBias)
{
  A += (long)blockIdx.z * sA;
  B += (long)blockIdx.z * sB;
  C += (long)blockIdx.z * sC;
  const float* bp = bias + (long)blockIdx.z * sBias;
  __shared__ float As[32][68];
  __shared__ float Bs[32][68];
  const int tid = threadIdx.x;
  const int tx = tid & 15, ty = tid >> 4;
  const int rowL = tid >> 3;
  const int colv = (tid & 7) << 2;
  const int m0 = blockIdx.x * 64, n0 = blockIdx.y * 64;
  float acc[4][4] = {};
  for (int k0 = 0; k0 < K; k0 += 32) {
#pragma unroll
    for (int it = 0; it < 2; it++) {
      const int r = rowL + it * 32;
      float4 v = *(const float4*)(A + (size_t)(m0 + r) * lda + k0 + colv);
      As[colv + 0][r] = v.x; As[colv + 1][r] = v.y; As[colv + 2][r] = v.z; As[colv + 3][r] = v.w;
      float4 w = *(const float4*)(B + (size_t)(n0 + r) * ldb + k0 + colv);
      Bs[colv + 0][r] = w.x; Bs[colv + 1][r] = w.y; Bs[colv + 2][r] = w.z; Bs[colv + 3][r] = w.w;
    }
    __syncthreads();
#pragma unroll
    for (int k = 0; k < 32; k++) {
      float4 a4 = *(const float4*)&As[k][ty * 4];
      float4 b4 = *(const float4*)&Bs[k][tx * 4];
      acc[0][0] += a4.x * b4.x; acc[0][1] += a4.x * b4.y; acc[0][2] += a4.x * b4.z; acc[0][3] += a4.x * b4.w;
      acc[1][0] += a4.y * b4.x; acc[1][1] += a4.y * b4.y; acc[1][2] += a4.y * b4.z; acc[1][3] += a4.y * b4.w;
      acc[2][0] += a4.z * b4.x; acc[2][1] += a4.z * b4.y; acc[2][2] += a4.z * b4.z; acc[2][3] += a4.z * b4.w;
      acc[3][0] += a4.w * b4.x; acc[3][1] += a4.w * b4.y; acc[3][2] += a4.w * b4.z; acc[3][3] += a4.w * b4.w;
    }
    __syncthreads();
  }
  float4 bv = make_float4(0.f, 0.f, 0.f, 0.f);
  if (addBias) bv = *(const float4*)(bp + n0 + tx * 4);
#pragma unroll
  for (int i = 0; i < 4; i++) {
    float4 o;
    o.x = acc[i][0] + bv.x; o.y = acc[i][1] + bv.y;
    o.z = acc[i][2] + bv.z; o.w = acc[i][3] + bv.w;
    *(float4*)(C + (size_t)(m0 + ty * 4 + i) * ldc + n0 + tx * 4) = o;
  }
}

// ---------------- LN(attn out) + entropy + z ----------------
__global__ __launch_bounds__(256) void ln_ent_kernel(
    const float* __restrict__ out2,
    const float* __restrict__ lng, const float* __restrict__ lnb,
    const float* __restrict__ ws, float* __restrict__ hcat,
    float* __restrict__ Hout, float* __restrict__ zout)
{
  const int r = blockIdx.x;
  const int mod = r >> 9, b = r & 511;
  const int tid = threadIdx.x, lane = tid & 63, wave = tid >> 6;
  __shared__ float red[4];
  const float* x = out2 + (size_t)r * 512;
  float2 v = *(const float2*)(x + 2 * tid);
  float s = blk_sum4(v.x + v.y, red, lane, wave);
  float sq = blk_sum4(v.x * v.x + v.y * v.y, red, lane, wave);
  float mean = s * (1.f / 512.f);
  float var = sq * (1.f / 512.f) - mean * mean;
  float rstd = rsqrtf(var + 1e-5f);
  float2 g = *(const float2*)(lng + 2 * tid);
  float2 bb = *(const float2*)(lnb + 2 * tid);
  float h0 = (v.x - mean) * rstd * g.x + bb.x;
  float h1 = (v.y - mean) * rstd * g.y + bb.y;
  *(float2*)(hcat + (size_t)b * 1536 + mod * 512 + 2 * tid) = make_float2(h0, h1);
  float2 ep = make_float2(0.f, 0.f);
#pragma unroll
  for (int j = 0; j < 8; j++) {
    float2 t = *(const float2*)(ws + WS_ENTP + j * 512 + 2 * tid);
    ep.x += t.x; ep.y += t.y;
  }
  ep.x *= (1.f / 512.f); ep.y *= (1.f / 512.f);
  float fa0 = fabsf(h0) + 1e-8f, fa1 = fabsf(h1) + 1e-8f;
  float S = blk_sum4(fa0 + fa1, red, lane, wave);
  float zz = blk_sum4(h0 * ep.x + h1 * ep.y, red, lane, wave);
  float invS = 1.f / S;
  float p0 = fa0 * invS, p1 = fa1 * invS;
  float t = blk_sum4(p0 * logf(p0 + 1e-8f) + p1 * logf(p1 + 1e-8f), red, lane, wave);
  if (tid == 0) {
    Hout[mod * 512 + b] = -t;
    zout[mod * 512 + b] = zz + ws[WS_ENTBM];
  }
}

// ---------------- gate LN/relu/sigmoid + entropy softmax + fuse ----------------
__global__ __launch_bounds__(256) void gate_fuse_kernel(
    const float* __restrict__ gpre, const float* __restrict__ glng, const float* __restrict__ glnb,
    const float* __restrict__ gw2, const float* __restrict__ gb2, const float* __restrict__ gb1,
    const float* __restrict__ araw, const float* __restrict__ hcat,
    const float* __restrict__ H, const float* __restrict__ z,
    float* __restrict__ hfused)
{
  const int b = blockIdx.x;
  const int tid = threadIdx.x, lane = tid & 63, wave = tid >> 6;
  __shared__ float red[4];
  float2 v;
  {
    float2 p0 = *(const float2*)(gpre + (size_t)b * 512 + 2 * tid);
    float2 p1 = *(const float2*)(gpre + 262144 + (size_t)b * 512 + 2 * tid);
    float2 p2 = *(const float2*)(gpre + 524288 + (size_t)b * 512 + 2 * tid);
    float2 bi = *(const float2*)(gb1 + 2 * tid);
    v.x = p0.x + p1.x + p2.x + bi.x;
    v.y = p0.y + p1.y + p2.y + bi.y;
  }
  float s = blk_sum4(v.x + v.y, red, lane, wave);
  float sq = blk_sum4(v.x * v.x + v.y * v.y, red, lane, wave);
  float mean = s * (1.f / 512.f), var = sq * (1.f / 512.f) - mean * mean;
  float rstd = rsqrtf(var + 1e-5f);
  float2 g = *(const float2*)(glng + 2 * tid);
  float2 bb = *(const float2*)(glnb + 2 * tid);
  float g0 = fmaxf((v.x - mean) * rstd * g.x + bb.x, 0.f);
  float g1 = fmaxf((v.y - mean) * rstd * g.y + bb.y, 0.f);
  float d0 = blk_sum4(g0 * gw2[2 * tid] + g1 * gw2[2 * tid + 1], red, lane, wave);
  float d1 = blk_sum4(g0 * gw2[512 + 2 * tid] + g1 * gw2[512 + 2 * tid + 1], red, lane, wave);
  float d2 = blk_sum4(g0 * gw2[1024 + 2 * tid] + g1 * gw2[1024 + 2 * tid + 1], red, lane, wave);
  float ga0 = 1.f / (1.f + __expf(-(d0 + gb2[0])));
  float ga1 = 1.f / (1.f + __expf(-(d1 + gb2[1])));
  float ga2 = 1.f / (1.f + __expf(-(d2 + gb2[2])));
  float sc0 = z[b] * __expf(-H[b]);
  float sc1 = z[512 + b] * __expf(-H[512 + b]);
  float sc2 = z[1024 + b] * __expf(-H[1024 + b]);
  float mxs = fmaxf(sc0, fmaxf(sc1, sc2));
  float e0 = __expf(sc0 - mxs), e1 = __expf(sc1 - mxs), e2 = __expf(sc2 - mxs);
  float inv = 1.f / (e0 + e1 + e2);
  e0 *= inv; e1 *= inv; e2 *= inv;
  float alpha = 1.f / (1.f + __expf(-araw[0]));
  const float* hb = hcat + (size_t)b * 1536 + 2 * tid;
  float2 hr = *(const float2*)hb;
  float2 hn = *(const float2*)(hb + 512);
  float2 ht = *(const float2*)(hb + 1024);
  float2 o;
  o.x = alpha * (e0 * hr.x + e1 * hn.x + e2 * ht.x)
      + (1.f - alpha) * (ga0 * hr.x + ga1 * hn.x + ga2 * ht.x);
  o.y = alpha * (e0 * hr.y + e1 * hn.y + e2 * ht.y)
      + (1.f - alpha) * (ga0 * hr.y + ga1 * hn.y + ga2 * ht.y);
  *(float2*)(hfused + (size_t)b * 512 + 2 * tid) = o;
}

// ---------------- final LN(enh) + concat-add ----------------
__global__ __launch_bounds__(256) void final_out_kernel(
    const float* __restrict__ epre, const float* __restrict__ enb,
    const float* __restrict__ elng, const float* __restrict__ elnb,
    const float* __restrict__ hcat, float* __restrict__ out)
{
  const int b = blockIdx.x;
  const int tid = threadIdx.x, lane = tid & 63, wave = tid >> 6;
  __shared__ float red[4];
  float2 v;
  {
    float2 p0 = *(const float2*)(epre + (size_t)b * 512 + 2 * tid);
    float2 p1 = *(const float2*)(epre + 262144 + (size_t)b * 512 + 2 * tid);
    float2 bi = *(const float2*)(enb + 2 * tid);
    v.x = p0.x + p1.x + bi.x;
    v.y = p0.y + p1.y + bi.y;
  }
  float s = blk_sum4(v.x + v.y, red, lane, wave);
  float sq = blk_sum4(v.x * v.x + v.y * v.y, red, lane, wave);
  float mean = s * (1.f / 512.f), var = sq * (1.f / 512.f) - mean * mean;
  float rstd = rsqrtf(var + 1e-5f);
  float2 g = *(const float2*)(elng + 2 * tid);
  float2 bb = *(const float2*)(elnb + 2 * tid);
  float e0 = (v.x - mean) * rstd * g.x + bb.x;
  float e1 = (v.y - mean) * rstd * g.y + bb.y;
  const float* hb = hcat + (size_t)b * 1536 + 2 * tid;
  float* ob = out + (size_t)b * 1536 + 2 * tid;
#pragma unroll
  for (int mm = 0; mm < 3; mm++) {
    float2 hv = *(const float2*)(hb + mm * 512);
    *(float2*)(ob + mm * 512) = make_float2(hv.x + e0, hv.y + e1);
  }
}

extern "C" void kernel_launch(void* const* d_in, const int* in_sizes, int n_in,
                              void* d_out, int out_size, void* d_ws, size_t ws_size,
                              hipStream_t stream)
{
  const float* trgb = (const float*)d_in[0];
  const float* tnir = (const float*)d_in[1];
  const float* ttir = (const float*)d_in[2];
  const float* qrgb = (const float*)d_in[3];
  const float* qnir = (const float*)d_in[4];
  const float* qtir = (const float*)d_in[5];
  const float* inw  = (const float*)d_in[6];
  const float* inb  = (const float*)d_in[7];
  const float* outw = (const float*)d_in[8];
  const float* outb = (const float*)d_in[9];
  const float* alng = (const float*)d_in[10];
  const float* alnb = (const float*)d_in[11];
  const float* entw = (const float*)d_in[12];
  const float* entb = (const float*)d_in[13];
  const float* gw1  = (const float*)d_in[14];
  const float* gb1  = (const float*)d_in[15];
  const float* glng = (const float*)d_in[16];
  const float* glnb = (const float*)d_in[17];
  const float* gw2  = (const float*)d_in[18];
  const float* gb2  = (const float*)d_in[19];
  const float* araw = (const float*)d_in[20];
  const float* enw  = (const float*)d_in[21];
  const float* enb  = (const float*)d_in[22];
  const float* elng = (const float*)d_in[23];
  const float* elnb = (const float*)d_in[24];
  float* ws = (float*)d_ws;
  float* out = (float*)d_out;

  hipLaunchKernelGGL(prep_kernel, dim3(4, 8), dim3(256), 0, stream,
                     qrgb, qnir, qtir, inw, inb, entw, entb, ws);
  hipLaunchKernelGGL(attn_pool_kernel, dim3(512, 3), dim3(256), 0, stream,
                     trgb, tnir, ttir, ws, ws + WS_P);
  // vout = P @ Wv^T + bv (batched over 8 heads)
  hipLaunchKernelGGL(gemm_bt_kernel, dim3(24, 1, 8), dim3(256), 0, stream,
                     ws + WS_P, inw + (size_t)1024 * 512, inb + 1024, ws + WS_VOUT,
                     512, 4096, 512, 512,
                     (long)512, (long)64 * 512, (long)64, 64, 1);
  // out2 = vout @ Wo^T + bo
  hipLaunchKernelGGL(gemm_bt_kernel, dim3(24, 8, 1), dim3(256), 0, stream,
                     ws + WS_VOUT, outw, outb, ws + WS_OUT2,
                     512, 512, 512, 512, 0L, 0L, 0L, 0, 1);
  hipLaunchKernelGGL(ln_ent_kernel, dim3(1536), dim3(256), 0, stream,
                     ws + WS_OUT2, alng, alnb, ws, ws + WS_HCAT, ws + WS_H, ws + WS_Z);
  // g_pre partials = hcat @ gate_w1^T (split-K x3, bias added in gate_fuse)
  hipLaunchKernelGGL(gemm_bt_kernel, dim3(8, 8, 3), dim3(256), 0, stream,
                     ws + WS_HCAT, gw1, gb1, ws + WS_GPRE,
                     512, 1536, 1536, 512,
                     (long)512, (long)512, (long)262144, 0, 0);
  hipLaunchKernelGGL(gate_fuse_kernel, dim3(512), dim3(256), 0, stream,
                     ws + WS_GPRE, glng, glnb, gw2, gb2, gb1, araw,
                     ws + WS_HCAT, ws + WS_H, ws + WS_Z, ws + WS_HFUSED);
  // enh partials = h_fused @ enh_w^T (split-K x2, bias added in final_out)
  hipLaunchKernelGGL(gemm_bt_kernel, dim3(8, 8, 2), dim3(256), 0, stream,
                     ws + WS_HFUSED, enw, enb, ws + WS_ENHPRE,
                     256, 512, 512, 512,
                     (long)256, (long)256, (long)262144, 0, 0);
  hipLaunchKernelGGL(final_out_kernel, dim3(512), dim3(256), 0, stream,
                     ws + WS_ENHPRE, enb, elng, elnb, ws + WS_HCAT, out);
}

// Round 6
// 287.518 us; speedup vs baseline: 3.7485x; 1.2843x over previous
//
#include <hip/hip_runtime.h>
#include <cstdint>

// ---------------- workspace layout (float offsets) ----------------
#define WS_U      0                          // 3*8*512 = 12288
#define WS_C0     12288                      // 24 (unused now)
#define WS_ENTBM  12312                      // 1
#define WS_ENTP   12320                      // 8*512 = 4096
#define WS_P      16416                      // 1536*4096 = 6291456
#define WS_OUT2   WS_P                       // alias (P dead after vout GEMM)
#define WS_GPRE   (WS_P + 786432)            // 3 partials * 262144
#define WS_HFUSED (WS_P + 1572864)           // 262144
#define WS_ENHPRE (WS_P + 1835008)           // 2 partials * 262144
#define WS_VOUT   (WS_P + 6291456)           // 786432
#define WS_HCAT   (WS_VOUT + 786432)         // 786432
#define WS_H      (WS_HCAT + 786432)         // 1536
#define WS_Z      (WS_H + 1536)              // 1536

__device__ __forceinline__ float blk_sum4(float v, float* red, int lane, int wave) {
#pragma unroll
  for (int off = 32; off; off >>= 1) v += __shfl_xor(v, off);
  __syncthreads();
  if (lane == 0) red[wave] = v;
  __syncthreads();
  return red[0] + red[1] + red[2] + red[3];
}

// ---------------- prep: grid (4, 8); m<3 -> u vectors, m==3 -> ent partials ----------------
__global__ __launch_bounds__(256) void prep_kernel(
    const float* __restrict__ qrgb, const float* __restrict__ qnir, const float* __restrict__ qtir,
    const float* __restrict__ inw, const float* __restrict__ inb,
    const float* __restrict__ entw, const float* __restrict__ entb,
    float* __restrict__ ws)
{
  const int m = blockIdx.x, h = blockIdx.y;
  const int tid = threadIdx.x, lane = tid & 63, wave = tid >> 6;
  __shared__ float qvl[64];
  __shared__ float red[4];

  if (m == 3) {
    const float* base = entw + (size_t)h * 64 * 512;
    float acc0 = 0.f, acc1 = 0.f;
#pragma unroll 8
    for (int r = 0; r < 64; r++) {
      acc0 += base[(size_t)r * 512 + tid];
      acc1 += base[(size_t)r * 512 + tid + 256];
    }
    ws[WS_ENTP + h * 512 + tid] = acc0;
    ws[WS_ENTP + h * 512 + tid + 256] = acc1;
    return;
  }

  const float* qry = (m == 0) ? qrgb : (m == 1) ? qnir : qtir;
  float4 q0 = *(const float4*)(qry + 4 * lane);
  float4 q1 = *(const float4*)(qry + 256 + 4 * lane);
#pragma unroll 4
  for (int dd = 0; dd < 16; dd++) {
    const int d = wave * 16 + dd;
    const float* wr = inw + (size_t)(h * 64 + d) * 512;
    float4 w0 = *(const float4*)(wr + 4 * lane);
    float4 w1 = *(const float4*)(wr + 256 + 4 * lane);
    float p = w0.x * q0.x + w0.y * q0.y + w0.z * q0.z + w0.w * q0.w
            + w1.x * q1.x + w1.y * q1.y + w1.z * q1.z + w1.w * q1.w;
#pragma unroll
    for (int off = 32; off; off >>= 1) p += __shfl_xor(p, off);
    if (lane == 0) qvl[d] = p + inb[h * 64 + d];
  }
  __syncthreads();
  float acc0 = 0.f, acc1 = 0.f;
  const float* wk = inw + (size_t)(512 + h * 64) * 512;
#pragma unroll 8
  for (int d = 0; d < 64; d++) {
    float qq = qvl[d];
    acc0 = fmaf(qq, wk[(size_t)d * 512 + tid], acc0);
    acc1 = fmaf(qq, wk[(size_t)d * 512 + tid + 256], acc1);
  }
  ws[WS_U + m * 4096 + h * 512 + tid] = 0.125f * acc0;
  ws[WS_U + m * 4096 + h * 512 + tid + 256] = 0.125f * acc1;
  if (m == 0 && h == 0) {
    float v = entb[tid] + entb[tid + 256];
    float s = blk_sum4(v, red, lane, wave);
    if (tid == 0) ws[WS_ENTBM] = s * (1.f / 512.f);
  }
}

// ---------------- attn_pool: 3-phase (scores -> exact softmax -> streaming pool) ----------------
// Phase S: 4-row batches, R4's verified transpose-reduce butterfly (ONE 6-deep chain
//   per 4 rows), raw scores -> sc[8][132] LDS. Write-only: no LDS roundtrip, no
//   online-softmax state. Tiny live set -> no spill (R4's spill was acc+arrays).
// Phase M: exact per-head softmax over L=129 (R0-verified code), in place.
// Phase P: pure streaming pool: coalesced float4 rows + broadcast float2 weights
//   from LDS, zero per-row dependency chain, depth-1 prefetch.
// Epilogue: plain sum of 4 per-wave partials (weights already normalized).
__global__ __launch_bounds__(256) void attn_pool_kernel(
    const float* __restrict__ trgb, const float* __restrict__ tnir, const float* __restrict__ ttir,
    const float* __restrict__ ws, float* __restrict__ Pout)
{
  const int b = blockIdx.x, m = blockIdx.y;
  const int tid = threadIdx.x, lane = tid & 63, wave = tid >> 6;
  const float* tok = ((m == 0) ? trgb : (m == 1) ? tnir : ttir) + (size_t)b * 129 * 512;
  const float* u = ws + WS_U + m * 4096;

  __shared__ float sc[8][132];        // raw scores -> softmax weights
  __shared__ float lacc[4][2][512];   // 16 KB combine stage (2 heads / round)

  const int b0 = lane & 1, b1 = (lane >> 1) & 1, b2 = (lane >> 2) & 1;
  const int b3 = (lane >> 3) & 1, b4 = (lane >> 4) & 1;
  const int r_own = (b0 << 1) | b1;                 // row-in-batch this lane owns
  const int h_own = (b2 << 2) | (b3 << 1) | b4;     // head this lane owns

  const int wbase = wave * 32;

#define LOADB(L0, A0, C0, A1, C1, A2, C2, A3, C3)                         \
  do {                                                                    \
    int r0_ = (L0), r1_ = (L0) + 1, r2_ = (L0) + 2, r3_ = (L0) + 3;       \
    if (r1_ > 128) r1_ = 128;                                             \
    if (r2_ > 128) r2_ = 128;                                             \
    if (r3_ > 128) r3_ = 128;                                             \
    const float* p0_ = tok + (size_t)r0_ * 512 + 4 * lane;                \
    const float* p1_ = tok + (size_t)r1_ * 512 + 4 * lane;                \
    const float* p2_ = tok + (size_t)r2_ * 512 + 4 * lane;                \
    const float* p3_ = tok + (size_t)r3_ * 512 + 4 * lane;                \
    A0 = *(const float4*)p0_; C0 = *(const float4*)(p0_ + 256);           \
    A1 = *(const float4*)p1_; C1 = *(const float4*)(p1_ + 256);           \
    A2 = *(const float4*)p2_; C2 = *(const float4*)(p2_ + 256);           \
    A3 = *(const float4*)p3_; C3 = *(const float4*)(p3_ + 256);           \
  } while (0)

  // by-value float4 params (SROA-safe, R1 precedent)
  auto score_batch = [&](int l0, bool tail,
                         float4 A0, float4 C0, float4 A1, float4 C1,
                         float4 A2, float4 C2, float4 A3, float4 C3) {
    float x[32];
#pragma unroll
    for (int h = 0; h < 8; h++) {
      float4 U0 = *(const float4*)(u + h * 512 + 4 * lane);
      float4 U1 = *(const float4*)(u + h * 512 + 256 + 4 * lane);
      x[h]      = A0.x * U0.x + A0.y * U0.y + A0.z * U0.z + A0.w * U0.w
                + C0.x * U1.x + C0.y * U1.y + C0.z * U1.z + C0.w * U1.w;
      x[8 + h]  = A1.x * U0.x + A1.y * U0.y + A1.z * U0.z + A1.w * U0.w
                + C1.x * U1.x + C1.y * U1.y + C1.z * U1.z + C1.w * U1.w;
      x[16 + h] = A2.x * U0.x + A2.y * U0.y + A2.z * U0.z + A2.w * U0.w
                + C2.x * U1.x + C2.y * U1.y + C2.z * U1.z + C2.w * U1.w;
      x[24 + h] = A3.x * U0.x + A3.y * U0.y + A3.z * U0.z + A3.w * U0.w
                + C3.x * U1.x + C3.y * U1.y + C3.z * U1.z + C3.w * U1.w;
    }
    // transpose-reduce butterfly (R4 hardware-verified): one 6-deep chain for all 32
#define MERGE_STAGE(n, M, bit)                                  \
    _Pragma("unroll")                                           \
    for (int j = 0; j < (n) / 2; j++) {                         \
      float keep = (bit) ? x[j + (n) / 2] : x[j];               \
      float send = (bit) ? x[j] : x[j + (n) / 2];               \
      x[j] = keep + __shfl_xor(send, (M));                      \
    }
    MERGE_STAGE(32, 1, b0)
    MERGE_STAGE(16, 2, b1)
    MERGE_STAGE(8, 4, b2)
    MERGE_STAGE(4, 8, b3)
    MERGE_STAGE(2, 16, b4)
#undef MERGE_STAGE
    float T = x[0] + __shfl_xor(x[0], 32);   // lane holds score of (r_own, h_own)
    if (lane < 32 && (!tail || r_own == 0))
      sc[h_own][l0 + r_own] = T;             // write-only; no roundtrip
  };

  // ---- phase S: scores, 8 batches of 4 rows, 1-batch-ahead prefetch ----
  {
    float4 A0, C0, A1, C1, A2, C2, A3, C3;
    float4 N0, D0, N1, D1, N2, D2, N3, D3;
    LOADB(wbase, A0, C0, A1, C1, A2, C2, A3, C3);
    for (int bt = 0; bt < 8; bt++) {
      if (bt < 7) LOADB(wbase + 4 * bt + 4, N0, D0, N1, D1, N2, D2, N3, D3);
      score_batch(wbase + 4 * bt, false, A0, C0, A1, C1, A2, C2, A3, C3);
      A0 = N0; C0 = D0; A1 = N1; C1 = D1;
      A2 = N2; C2 = D2; A3 = N3; C3 = D3;
    }
    if (wave == 0) {   // row 128: clamped batch, only r_own==0 written
      LOADB(128, A0, C0, A1, C1, A2, C2, A3, C3);
      score_batch(128, true, A0, C0, A1, C1, A2, C2, A3, C3);
    }
  }
  __syncthreads();

  // ---- phase M: exact per-head softmax over 129 (R0-verified), in place ----
#pragma unroll
  for (int hh = 0; hh < 2; hh++) {
    const int h = wave * 2 + hh;
    float x0 = sc[h][lane];
    float x1 = sc[h][64 + lane];
    float x2 = (lane == 0) ? sc[h][128] : -3.0e38f;
    float mx = fmaxf(fmaxf(x0, x1), x2);
#pragma unroll
    for (int off = 32; off; off >>= 1) mx = fmaxf(mx, __shfl_xor(mx, off));
    float e0 = __expf(x0 - mx), e1 = __expf(x1 - mx);
    float e2 = (lane == 0) ? __expf(x2 - mx) : 0.f;
    float s = e0 + e1 + e2;
#pragma unroll
    for (int off = 32; off; off >>= 1) s += __shfl_xor(s, off);
    float inv = 1.f / s;
    sc[h][lane] = e0 * inv;
    sc[h][64 + lane] = e1 * inv;
    if (lane == 0) sc[h][128] = e2 * inv;
  }
  __syncthreads();

  // ---- phase P: streaming pool, no per-row dependency ----
  float acc[8][8];
#pragma unroll
  for (int h = 0; h < 8; h++)
#pragma unroll
    for (int j = 0; j < 8; j++) acc[h][j] = 0.f;
  {
    float4 pa0, pc0, pa1, pc1, qa0, qc0, qa1, qc1;
    {
      const float* p0 = tok + (size_t)wbase * 512 + 4 * lane;
      const float* p1 = tok + (size_t)(wbase + 1) * 512 + 4 * lane;
      pa0 = *(const float4*)p0; pc0 = *(const float4*)(p0 + 256);
      pa1 = *(const float4*)p1; pc1 = *(const float4*)(p1 + 256);
    }
    for (int g = 0; g < 16; g++) {
      if (g < 15) {
        const float* p0 = tok + (size_t)(wbase + 2 * g + 2) * 512 + 4 * lane;
        const float* p1 = tok + (size_t)(wbase + 2 * g + 3) * 512 + 4 * lane;
        qa0 = *(const float4*)p0; qc0 = *(const float4*)(p0 + 256);
        qa1 = *(const float4*)p1; qc1 = *(const float4*)(p1 + 256);
      }
#pragma unroll
      for (int h = 0; h < 8; h++) {
        float2 w2 = *(const float2*)&sc[h][wbase + 2 * g];
        acc[h][0] = fmaf(w2.x, pa0.x, acc[h][0]);
        acc[h][1] = fmaf(w2.x, pa0.y, acc[h][1]);
        acc[h][2] = fmaf(w2.x, pa0.z, acc[h][2]);
        acc[h][3] = fmaf(w2.x, pa0.w, acc[h][3]);
        acc[h][4] = fmaf(w2.x, pc0.x, acc[h][4]);
        acc[h][5] = fmaf(w2.x, pc0.y, acc[h][5]);
        acc[h][6] = fmaf(w2.x, pc0.z, acc[h][6]);
        acc[h][7] = fmaf(w2.x, pc0.w, acc[h][7]);
        acc[h][0] = fmaf(w2.y, pa1.x, acc[h][0]);
        acc[h][1] = fmaf(w2.y, pa1.y, acc[h][1]);
        acc[h][2] = fmaf(w2.y, pa1.z, acc[h][2]);
        acc[h][3] = fmaf(w2.y, pa1.w, acc[h][3]);
        acc[h][4] = fmaf(w2.y, pc1.x, acc[h][4]);
        acc[h][5] = fmaf(w2.y, pc1.y, acc[h][5]);
        acc[h][6] = fmaf(w2.y, pc1.z, acc[h][6]);
        acc[h][7] = fmaf(w2.y, pc1.w, acc[h][7]);
      }
      pa0 = qa0; pc0 = qc0; pa1 = qa1; pc1 = qc1;
    }
    if (wave == 0) {   // row 128
      const float* p0 = tok + (size_t)128 * 512 + 4 * lane;
      float4 ta = *(const float4*)p0;
      float4 tc = *(const float4*)(p0 + 256);
#pragma unroll
      for (int h = 0; h < 8; h++) {
        float wt = sc[h][128];
        acc[h][0] = fmaf(wt, ta.x, acc[h][0]);
        acc[h][1] = fmaf(wt, ta.y, acc[h][1]);
        acc[h][2] = fmaf(wt, ta.z, acc[h][2]);
        acc[h][3] = fmaf(wt, ta.w, acc[h][3]);
        acc[h][4] = fmaf(wt, tc.x, acc[h][4]);
        acc[h][5] = fmaf(wt, tc.y, acc[h][5]);
        acc[h][6] = fmaf(wt, tc.z, acc[h][6]);
        acc[h][7] = fmaf(wt, tc.w, acc[h][7]);
      }
    }
  }
#undef LOADB

  // ---- epilogue: plain sum of 4 per-wave partials, 4 rounds x 2 heads ----
  float* po = Pout + (size_t)(m * 512 + b) * 4096 + 2 * tid;
#pragma unroll
  for (int hb = 0; hb < 8; hb += 2) {
    __syncthreads();                  // previous round's reads (or phase P) done
#pragma unroll
    for (int hh = 0; hh < 2; hh++) {
      const int h = hb + hh;
      *(float4*)&lacc[wave][hh][4 * lane] =
          make_float4(acc[h][0], acc[h][1], acc[h][2], acc[h][3]);
      *(float4*)&lacc[wave][hh][256 + 4 * lane] =
          make_float4(acc[h][4], acc[h][5], acc[h][6], acc[h][7]);
    }
    __syncthreads();
#pragma unroll
    for (int hh = 0; hh < 2; hh++) {
      const int h = hb + hh;
      float2 x0 = *(const float2*)&lacc[0][hh][2 * tid];
      float2 x1 = *(const float2*)&lacc[1][hh][2 * tid];
      float2 x2 = *(const float2*)&lacc[2][hh][2 * tid];
      float2 x3 = *(const float2*)&lacc[3][hh][2 * tid];
      *(float2*)(po + h * 512) =
          make_float2(x0.x + x1.x + x2.x + x3.x, x0.y + x1.y + x2.y + x3.y);
    }
  }
}

// ---------------- f32 GEMM: C = A @ B^T (+bias), 64x64 tile, 4x4 micro ----------------
__global__ __launch_bounds__(256) void gemm_bt_kernel(
    const float* __restrict__ A, const float* __restrict__ B,
    const float* __restrict__ bias, float* __restrict__ C,
    int K, int lda, int ldb, int ldc,
    long sA, long sB, long sC, int sBias, int addBias)
{
  A += (long)blockIdx.z * sA;
  B += (long)blockIdx.z * sB;
  C += (long)blockIdx.z * sC;
  const float* bp = bias + (long)blockIdx.z * sBias;
  __shared__ float As[32][68];
  __shared__ float Bs[32][68];
  const int tid = threadIdx.x;
  const int tx = tid & 15, ty = tid >> 4;
  const int rowL = tid >> 3;
  const int colv = (tid & 7) << 2;
  const int m0 = blockIdx.x * 64, n0 = blockIdx.y * 64;
  float acc[4][4] = {};
  for (int k0 = 0; k0 < K; k0 += 32) {
#pragma unroll
    for (int it = 0; it < 2; it++) {
      const int r = rowL + it * 32;
      float4 v = *(const float4*)(A + (size_t)(m0 + r) * lda + k0 + colv);
      As[colv + 0][r] = v.x; As[colv + 1][r] = v.y; As[colv + 2][r] = v.z; As[colv + 3][r] = v.w;
      float4 w = *(const float4*)(B + (size_t)(n0 + r) * ldb + k0 + colv);
      Bs[colv + 0][r] = w.x; Bs[colv + 1][r] = w.y; Bs[colv + 2][r] = w.z; Bs[colv + 3][r] = w.w;
    }
    __syncthreads();
#pragma unroll
    for (int k = 0; k < 32; k++) {
      float4 a4 = *(const float4*)&As[k][ty * 4];
      float4 b4 = *(const float4*)&Bs[k][tx * 4];
      acc[0][0] += a4.x * b4.x; acc[0][1] += a4.x * b4.y; acc[0][2] += a4.x * b4.z; acc[0][3] += a4.x * b4.w;
      acc[1][0] += a4.y * b4.x; acc[1][1] += a4.y * b4.y; acc[1][2] += a4.y * b4.z; acc[1][3] += a4.y * b4.w;
      acc[2][0] += a4.z * b4.x; acc[2][1] += a4.z * b4.y; acc[2][2] += a4.z * b4.z; acc[2][3] += a4.z * b4.w;
      acc[3][0] += a4.w * b4.x; acc[3][1] += a4.w * b4.y; acc[3][2] += a4.w * b4.z; acc[3][3] += a4.w * b4.w;
    }
    __syncthreads();
  }
  float4 bv = make_float4(0.f, 0.f, 0.f, 0.f);
  if (addBias) bv = *(const float4*)(bp + n0 + tx * 4);
#pragma unroll
  for (int i = 0; i < 4; i++) {
    float4 o;
    o.x = acc[i][0] + bv.x; o.y = acc[i][1] + bv.y;
    o.z = acc[i][2] + bv.z; o.w = acc[i][3] + bv.w;
    *(float4*)(C + (size_t)(m0 + ty * 4 + i) * ldc + n0 + tx * 4) = o;
  }
}

// ---------------- LN(attn out) + entropy + z ----------------
__global__ __launch_bounds__(256) void ln_ent_kernel(
    const float* __restrict__ out2,
    const float* __restrict__ lng, const float* __restrict__ lnb,
    const float* __restrict__ ws, float* __restrict__ hcat,
    float* __restrict__ Hout, float* __restrict__ zout)
{
  const int r = blockIdx.x;
  const int mod = r >> 9, b = r & 511;
  const int tid = threadIdx.x, lane = tid & 63, wave = tid >> 6;
  __shared__ float red[4];
  const float* x = out2 + (size_t)r * 512;
  float2 v = *(const float2*)(x + 2 * tid);
  float s = blk_sum4(v.x + v.y, red, lane, wave);
  float sq = blk_sum4(v.x * v.x + v.y * v.y, red, lane, wave);
  float mean = s * (1.f / 512.f);
  float var = sq * (1.f / 512.f) - mean * mean;
  float rstd = rsqrtf(var + 1e-5f);
  float2 g = *(const float2*)(lng + 2 * tid);
  float2 bb = *(const float2*)(lnb + 2 * tid);
  float h0 = (v.x - mean) * rstd * g.x + bb.x;
  float h1 = (v.y - mean) * rstd * g.y + bb.y;
  *(float2*)(hcat + (size_t)b * 1536 + mod * 512 + 2 * tid) = make_float2(h0, h1);
  float2 ep = make_float2(0.f, 0.f);
#pragma unroll
  for (int j = 0; j < 8; j++) {
    float2 t = *(const float2*)(ws + WS_ENTP + j * 512 + 2 * tid);
    ep.x += t.x; ep.y += t.y;
  }
  ep.x *= (1.f / 512.f); ep.y *= (1.f / 512.f);
  float fa0 = fabsf(h0) + 1e-8f, fa1 = fabsf(h1) + 1e-8f;
  float S = blk_sum4(fa0 + fa1, red, lane, wave);
  float zz = blk_sum4(h0 * ep.x + h1 * ep.y, red, lane, wave);
  float invS = 1.f / S;
  float p0 = fa0 * invS, p1 = fa1 * invS;
  float t = blk_sum4(p0 * logf(p0 + 1e-8f) + p1 * logf(p1 + 1e-8f), red, lane, wave);
  if (tid == 0) {
    Hout[mod * 512 + b] = -t;
    zout[mod * 512 + b] = zz + ws[WS_ENTBM];
  }
}

// ---------------- gate LN/relu/sigmoid + entropy softmax + fuse ----------------
__global__ __launch_bounds__(256) void gate_fuse_kernel(
    const float* __restrict__ gpre, const float* __restrict__ glng, const float* __restrict__ glnb,
    const float* __restrict__ gw2, const float* __restrict__ gb2, const float* __restrict__ gb1,
    const float* __restrict__ araw, const float* __restrict__ hcat,
    const float* __restrict__ H, const float* __restrict__ z,
    float* __restrict__ hfused)
{
  const int b = blockIdx.x;
  const int tid = threadIdx.x, lane = tid & 63, wave = tid >> 6;
  __shared__ float red[4];
  float2 v;
  {
    float2 p0 = *(const float2*)(gpre + (size_t)b * 512 + 2 * tid);
    float2 p1 = *(const float2*)(gpre + 262144 + (size_t)b * 512 + 2 * tid);
    float2 p2 = *(const float2*)(gpre + 524288 + (size_t)b * 512 + 2 * tid);
    float2 bi = *(const float2*)(gb1 + 2 * tid);
    v.x = p0.x + p1.x + p2.x + bi.x;
    v.y = p0.y + p1.y + p2.y + bi.y;
  }
  float s = blk_sum4(v.x + v.y, red, lane, wave);
  float sq = blk_sum4(v.x * v.x + v.y * v.y, red, lane, wave);
  float mean = s * (1.f / 512.f), var = sq * (1.f / 512.f) - mean * mean;
  float rstd = rsqrtf(var + 1e-5f);
  float2 g = *(const float2*)(glng + 2 * tid);
  float2 bb = *(const float2*)(glnb + 2 * tid);
  float g0 = fmaxf((v.x - mean) * rstd * g.x + bb.x, 0.f);
  float g1 = fmaxf((v.y - mean) * rstd * g.y + bb.y, 0.f);
  float d0 = blk_sum4(g0 * gw2[2 * tid] + g1 * gw2[2 * tid + 1], red, lane, wave);
  float d1 = blk_sum4(g0 * gw2[512 + 2 * tid] + g1 * gw2[512 + 2 * tid + 1], red, lane, wave);
  float d2 = blk_sum4(g0 * gw2[1024 + 2 * tid] + g1 * gw2[1024 + 2 * tid + 1], red, lane, wave);
  float ga0 = 1.f / (1.f + __expf(-(d0 + gb2[0])));
  float ga1 = 1.f / (1.f + __expf(-(d1 + gb2[1])));
  float ga2 = 1.f / (1.f + __expf(-(d2 + gb2[2])));
  float sc0 = z[b] * __expf(-H[b]);
  float sc1 = z[512 + b] * __expf(-H[512 + b]);
  float sc2 = z[1024 + b] * __expf(-H[1024 + b]);
  float mxs = fmaxf(sc0, fmaxf(sc1, sc2));
  float e0 = __expf(sc0 - mxs), e1 = __expf(sc1 - mxs), e2 = __expf(sc2 - mxs);
  float inv = 1.f / (e0 + e1 + e2);
  e0 *= inv; e1 *= inv; e2 *= inv;
  float alpha = 1.f / (1.f + __expf(-araw[0]));
  const float* hb = hcat + (size_t)b * 1536 + 2 * tid;
  float2 hr = *(const float2*)hb;
  float2 hn = *(const float2*)(hb + 512);
  float2 ht = *(const float2*)(hb + 1024);
  float2 o;
  o.x = alpha * (e0 * hr.x + e1 * hn.x + e2 * ht.x)
      + (1.f - alpha) * (ga0 * hr.x + ga1 * hn.x + ga2 * ht.x);
  o.y = alpha * (e0 * hr.y + e1 * hn.y + e2 * ht.y)
      + (1.f - alpha) * (ga0 * hr.y + ga1 * hn.y + ga2 * ht.y);
  *(float2*)(hfused + (size_t)b * 512 + 2 * tid) = o;
}

// ---------------- final LN(enh) + concat-add ----------------
__global__ __launch_bounds__(256) void final_out_kernel(
    const float* __restrict__ epre, const float* __restrict__ enb,
    const float* __restrict__ elng, const float* __restrict__ elnb,
    const float* __restrict__ hcat, float* __restrict__ out)
{
  const int b = blockIdx.x;
  const int tid = threadIdx.x, lane = tid & 63, wave = tid >> 6;
  __shared__ float red[4];
  float2 v;
  {
    float2 p0 = *(const float2*)(epre + (size_t)b * 512 + 2 * tid);
    float2 p1 = *(const float2*)(epre + 262144 + (size_t)b * 512 + 2 * tid);
    float2 bi = *(const float2*)(enb + 2 * tid);
    v.x = p0.x + p1.x + bi.x;
    v.y = p0.y + p1.y + bi.y;
  }
  float s = blk_sum4(v.x + v.y, red, lane, wave);
  float sq = blk_sum4(v.x * v.x + v.y * v.y, red, lane, wave);
  float mean = s * (1.f / 512.f), var = sq * (1.f / 512.f) - mean * mean;
  float rstd = rsqrtf(var + 1e-5f);
  float2 g = *(const float2*)(elng + 2 * tid);
  float2 bb = *(const float2*)(elnb + 2 * tid);
  float e0 = (v.x - mean) * rstd * g.x + bb.x;
  float e1 = (v.y - mean) * rstd * g.y + bb.y;
  const float* hb = hcat + (size_t)b * 1536 + 2 * tid;
  float* ob = out + (size_t)b * 1536 + 2 * tid;
#pragma unroll
  for (int mm = 0; mm < 3; mm++) {
    float2 hv = *(const float2*)(hb + mm * 512);
    *(float2*)(ob + mm * 512) = make_float2(hv.x + e0, hv.y + e1);
  }
}

extern "C" void kernel_launch(void* const* d_in, const int* in_sizes, int n_in,
                              void* d_out, int out_size, void* d_ws, size_t ws_size,
                              hipStream_t stream)
{
  const float* trgb = (const float*)d_in[0];
  const float* tnir = (const float*)d_in[1];
  const float* ttir = (const float*)d_in[2];
  const float* qrgb = (const float*)d_in[3];
  const float* qnir = (const float*)d_in[4];
  const float* qtir = (const float*)d_in[5];
  const float* inw  = (const float*)d_in[6];
  const float* inb  = (const float*)d_in[7];
  const float* outw = (const float*)d_in[8];
  const float* outb = (const float*)d_in[9];
  const float* alng = (const float*)d_in[10];
  const float* alnb = (const float*)d_in[11];
  const float* entw = (const float*)d_in[12];
  const float* entb = (const float*)d_in[13];
  const float* gw1  = (const float*)d_in[14];
  const float* gb1  = (const float*)d_in[15];
  const float* glng = (const float*)d_in[16];
  const float* glnb = (const float*)d_in[17];
  const float* gw2  = (const float*)d_in[18];
  const float* gb2  = (const float*)d_in[19];
  const float* araw = (const float*)d_in[20];
  const float* enw  = (const float*)d_in[21];
  const float* enb  = (const float*)d_in[22];
  const float* elng = (const float*)d_in[23];
  const float* elnb = (const float*)d_in[24];
  float* ws = (float*)d_ws;
  float* out = (float*)d_out;

  hipLaunchKernelGGL(prep_kernel, dim3(4, 8), dim3(256), 0, stream,
                     qrgb, qnir, qtir, inw, inb, entw, entb, ws);
  hipLaunchKernelGGL(attn_pool_kernel, dim3(512, 3), dim3(256), 0, stream,
                     trgb, tnir, ttir, ws, ws + WS_P);
  // vout = P @ Wv^T + bv (batched over 8 heads)
  hipLaunchKernelGGL(gemm_bt_kernel, dim3(24, 1, 8), dim3(256), 0, stream,
                     ws + WS_P, inw + (size_t)1024 * 512, inb + 1024, ws + WS_VOUT,
                     512, 4096, 512, 512,
                     (long)512, (long)64 * 512, (long)64, 64, 1);
  // out2 = vout @ Wo^T + bo
  hipLaunchKernelGGL(gemm_bt_kernel, dim3(24, 8, 1), dim3(256), 0, stream,
                     ws + WS_VOUT, outw, outb, ws + WS_OUT2,
                     512, 512, 512, 512, 0L, 0L, 0L, 0, 1);
  hipLaunchKernelGGL(ln_ent_kernel, dim3(1536), dim3(256), 0, stream,
                     ws + WS_OUT2, alng, alnb, ws, ws + WS_HCAT, ws + WS_H, ws + WS_Z);
  // g_pre partials = hcat @ gate_w1^T (split-K x3, bias added in gate_fuse)
  hipLaunchKernelGGL(gemm_bt_kernel, dim3(8, 8, 3), dim3(256), 0, stream,
                     ws + WS_HCAT, gw1, gb1, ws + WS_GPRE,
                     512, 1536, 1536, 512,
                     (long)512, (long)512, (long)262144, 0, 0);
  hipLaunchKernelGGL(gate_fuse_kernel, dim3(512), dim3(256), 0, stream,
                     ws + WS_GPRE, glng, glnb, gw2, gb2, gb1, araw,
                     ws + WS_HCAT, ws + WS_H, ws + WS_Z, ws + WS_HFUSED);
  // enh partials = h_fused @ enh_w^T (split-K x2, bias added in final_out)
  hipLaunchKernelGGL(gemm_bt_kernel, dim3(8, 8, 2), dim3(256), 0, stream,
                     ws + WS_HFUSED, enw, enb, ws + WS_ENHPRE,
                     256, 512, 512, 512,
                     (long)256, (long)256, (long)262144, 0, 0);
  hipLaunchKernelGGL(final_out_kernel, dim3(512), dim3(256), 0, stream,
                     ws + WS_ENHPRE, enb, elng, elnb, ws + WS_HCAT, out);
}